// Round 4
// baseline (711.145 us; speedup 1.0000x reference)
//
#include <hip/hip_runtime.h>

// GCN 2-layer, CSR-gather formulation, bucket-sorted CSR build (no fp32
// atomics anywhere; no random scattered writes).
//   out[c] = dinv[c] * ( h_s[c] + sum_{e: col=c} h_s[row_e] ) + b,  h_s=(X@W)*dinv
// CSR build: (A) 782-bucket histogram (col>>7) + scan + append-scatter of
// packed (col&127, row) entries -> bucket regions (sequential-per-bucket
// writes, line-coalesced); (B) per-bucket LDS counting sort -> offsets, dinv,
// eros written sequentially. Requires N < 2^17 (row packed in 17 bits).
// Harness delivers integer inputs as int32.

#define BKT_SH 7            // 128 nodes per bucket
#define BKT_CAP 6144        // max edges per bucket (avg ~2046, std ~45)

__global__ __launch_bounds__(256) void k_zero_i(int* __restrict__ p, int n) {
    int i = blockIdx.x * 256 + threadIdx.x;
    if (i < n) p[i] = 0;
}

// (A1) coarse histogram via per-block LDS hist, merged with global atomics.
__global__ __launch_bounds__(256) void k_bhist(const int* __restrict__ col,
                                               int* __restrict__ bhist,
                                               int nb, int E) {
    __shared__ int h[1024];
    for (int i = threadIdx.x; i < nb; i += 256) h[i] = 0;
    __syncthreads();
    int stride = gridDim.x * 256;
    for (int i = blockIdx.x * 256 + threadIdx.x; i < E; i += stride)
        atomicAdd(&h[col[i] >> BKT_SH], 1);
    __syncthreads();
    for (int i = threadIdx.x; i < nb; i += 256)
        if (h[i]) atomicAdd(&bhist[i], h[i]);
}

// (A2) single-block exclusive scan of nb (<=1024) bucket counts.
__global__ __launch_bounds__(1024) void k_bscan(const int* __restrict__ bhist,
                                                int* __restrict__ bucket_base,
                                                int* __restrict__ cursor,
                                                int nb, int E) {
    __shared__ int s[1024];
    int t = threadIdx.x;
    int v = (t < nb) ? bhist[t] : 0;
    s[t] = v;
    __syncthreads();
#pragma unroll
    for (int d = 1; d < 1024; d <<= 1) {
        int x = (t >= d) ? s[t - d] : 0;
        __syncthreads();
        if (t >= d) s[t] += x;
        __syncthreads();
    }
    if (t < nb) {
        int ex = s[t] - v;
        bucket_base[t] = ex;
        cursor[t] = ex;
    }
    if (t == 0) bucket_base[nb] = E;
}

// (A3) append-scatter packed entries into bucket regions.
__global__ __launch_bounds__(256) void k_bscatter(const int* __restrict__ row,
                                                  const int* __restrict__ col,
                                                  int* __restrict__ cursor,
                                                  unsigned* __restrict__ bentries,
                                                  int E) {
    int i = blockIdx.x * 256 + threadIdx.x;
    if (i >= E) return;
    int c = col[i];
    int p = atomicAdd(&cursor[c >> BKT_SH], 1);
    bentries[p] = ((unsigned)(c & ((1 << BKT_SH) - 1)) << 17) | (unsigned)row[i];
}

// (B) per-bucket counting sort: offsets, dinv, eros (all sequential writes).
__global__ __launch_bounds__(256) void k_bucket_sort(
    const unsigned* __restrict__ bentries, const int* __restrict__ bucket_base,
    int* __restrict__ offsets, float* __restrict__ dinv,
    int* __restrict__ eros, int N, int E) {
    __shared__ int hist[128];
    __shared__ int incl[128];
    __shared__ int cur[128];
    __shared__ int rows[BKT_CAP];
    int b = blockIdx.x, t = threadIdx.x;
    int base = bucket_base[b];
    int cnt = bucket_base[b + 1] - base;
    if (cnt > BKT_CAP) cnt = BKT_CAP;  // safety clamp (never expected)

    if (t < 128) hist[t] = 0;
    __syncthreads();
    for (int i = t; i < cnt; i += 256)
        atomicAdd(&hist[bentries[base + i] >> 17], 1);
    __syncthreads();
    if (t < 128) incl[t] = hist[t];
    __syncthreads();
#pragma unroll
    for (int d = 1; d < 128; d <<= 1) {
        int x = (t < 128 && t >= d) ? incl[t - d] : 0;
        __syncthreads();
        if (t < 128 && t >= d) incl[t] += x;
        __syncthreads();
    }
    if (t < 128) {
        int ex = incl[t] - hist[t];  // exclusive within bucket
        int node = (b << BKT_SH) + t;
        if (node <= N) offsets[node] = base + ex;  // node==N lands on E
        if (node < N) dinv[node] = rsqrtf((float)hist[t] + 1.0f);
        cur[t] = ex;
    }
    __syncthreads();
    for (int i = t; i < cnt; i += 256) {
        unsigned en = bentries[base + i];
        int p = atomicAdd(&cur[en >> 17], 1);
        rows[p] = (int)(en & 0x1FFFF);
    }
    __syncthreads();
    for (int i = t; i < cnt; i += 256) eros[base + i] = rows[i];
}

// out[i][c] = (sum_k X[i][k] * W[k][c]) * dinv[i],  c in [0,64). K = 128 or 64.
// One thread per row, 64 fp32 accumulators, W staged in LDS (<=32 KB).
__global__ __launch_bounds__(256) void k_gemm_rowscale(
    const float* __restrict__ X, const float* __restrict__ W,
    const float* __restrict__ dinv, float* __restrict__ out, int N, int K) {
    __shared__ float w_lds[128 * 64];
    int tid = threadIdx.x;
    int nv4 = K * 16;
    for (int i = tid; i < nv4; i += 256)
        ((float4*)w_lds)[i] = ((const float4*)W)[i];
    __syncthreads();
    int row = blockIdx.x * 256 + tid;
    if (row >= N) return;

    float acc[64];
#pragma unroll
    for (int c = 0; c < 64; ++c) acc[c] = 0.f;

    const float4* xr = (const float4*)(X + (size_t)row * K);
    int K4 = K >> 2;
    for (int k4 = 0; k4 < K4; ++k4) {
        float4 xv = xr[k4];
        const float* wk = w_lds + (k4 << 8);
#pragma unroll
        for (int kk = 0; kk < 4; ++kk) {
            float xk = kk == 0 ? xv.x : kk == 1 ? xv.y : kk == 2 ? xv.z : xv.w;
            const float4* wrow = (const float4*)(wk + kk * 64);
#pragma unroll
            for (int c4 = 0; c4 < 16; ++c4) {
                float4 w = wrow[c4];
                acc[c4 * 4 + 0] = fmaf(xk, w.x, acc[c4 * 4 + 0]);
                acc[c4 * 4 + 1] = fmaf(xk, w.y, acc[c4 * 4 + 1]);
                acc[c4 * 4 + 2] = fmaf(xk, w.z, acc[c4 * 4 + 2]);
                acc[c4 * 4 + 3] = fmaf(xk, w.w, acc[c4 * 4 + 3]);
            }
        }
    }
    float s = dinv[row];
    float4* o = (float4*)(out + (size_t)row * 64);
#pragma unroll
    for (int c4 = 0; c4 < 16; ++c4) {
        float4 v;
        v.x = acc[c4 * 4 + 0] * s;
        v.y = acc[c4 * 4 + 1] * s;
        v.z = acc[c4 * 4 + 2] * s;
        v.w = acc[c4 * 4 + 3] * s;
        o[c4] = v;
    }
}

// Gather-aggregate + fused postproc. One 16-lane group per node; lane l owns
// channels [4l, 4l+4). acc init = src[node] (self loop). No atomics.
__global__ __launch_bounds__(256) void k_gather(
    const float* __restrict__ src, const int* __restrict__ offsets,
    const int* __restrict__ eros, const float* __restrict__ dinv,
    const float* __restrict__ bias, float* __restrict__ dst, int N, int do_relu) {
    int idx = blockIdx.x * 256 + threadIdx.x;
    int node = idx >> 4;
    if (node >= N) return;
    int l = idx & 15;

    const float4* s4 = (const float4*)src;
    float4 acc = s4[(size_t)node * 16 + l];  // self loop
    int e = offsets[node], eend = offsets[node + 1];
    for (; e < eend; ++e) {
        int r = eros[e];
        float4 v = s4[(size_t)r * 16 + l];
        acc.x += v.x; acc.y += v.y; acc.z += v.z; acc.w += v.w;
    }
    float sc = dinv[node];
    float4 b = ((const float4*)bias)[l];
    acc.x = acc.x * sc + b.x;
    acc.y = acc.y * sc + b.y;
    acc.z = acc.z * sc + b.z;
    acc.w = acc.w * sc + b.w;
    if (do_relu) {
        acc.x = fmaxf(acc.x, 0.f);
        acc.y = fmaxf(acc.y, 0.f);
        acc.z = fmaxf(acc.z, 0.f);
        acc.w = fmaxf(acc.w, 0.f);
    }
    ((float4*)dst)[(size_t)node * 16 + l] = acc;
}

extern "C" void kernel_launch(void* const* d_in, const int* in_sizes, int n_in,
                              void* d_out, int out_size, void* d_ws, size_t ws_size,
                              hipStream_t stream) {
    const float* x = (const float*)d_in[0];
    const int* ei = (const int*)d_in[1];  // int32 per harness contract, [2, E]
    const float* W1 = (const float*)d_in[2];
    const float* b1 = (const float*)d_in[3];
    const float* W2 = (const float*)d_in[4];
    const float* b2 = (const float*)d_in[5];

    int N = in_sizes[0] / 128;  // 100000
    int E = in_sizes[1] / 2;    // 1600000
    const int* row = ei;
    const int* col = ei + E;
    int nb = (N + (1 << BKT_SH) - 1) >> BKT_SH;  // 782 buckets

    char* ws = (char*)d_ws;
    int* bhist = (int*)ws;                          // <=1024 ints @ 0
    int* bucket_base = (int*)(ws + (1 << 14));      // <=1025 ints @ 16 KB
    int* cursor = (int*)(ws + (1 << 15));           // <=1024 ints @ 32 KB
    int* offsets = (int*)(ws + (1 << 16));          // N+1 ints @ 64 KB
    float* dinv = (float*)(ws + 576 * 1024);        // N floats @ 576 KB
    // bentries (6.4 MB) overlaps A's region: dead before A is first written.
    unsigned* bentries = (unsigned*)(ws + (2 << 20));  // E u32 @ 2 MB
    float* A = (float*)(ws + (2 << 20));            // N*64 floats @ 2 MB (25.6 MB)
    int* eros = (int*)(ws + (28 << 20));            // E ints @ 28 MB (6.4 MB)
    float* OUT = (float*)d_out;                     // N*64 floats, 2nd buffer

    int nblk = (N + 255) / 256;
    int eblk = (E + 255) / 256;

    // --- CSR build (bucket sort; once, shared by both layers) ---
    k_zero_i<<<(nb + 255) / 256, 256, 0, stream>>>(bhist, nb);
    k_bhist<<<320, 256, 0, stream>>>(col, bhist, nb, E);
    k_bscan<<<1, 1024, 0, stream>>>(bhist, bucket_base, cursor, nb, E);
    k_bscatter<<<eblk, 256, 0, stream>>>(row, col, cursor, bentries, E);
    k_bucket_sort<<<nb, 256, 0, stream>>>(bentries, bucket_base, offsets, dinv,
                                          eros, N, E);

    int gblk = (N * 16 + 255) / 256;

    // Layer 1: A = (X@W1)*dinv; OUT = relu(gather(A)*dinv + b1)
    k_gemm_rowscale<<<nblk, 256, 0, stream>>>(x, W1, dinv, A, N, 128);
    k_gather<<<gblk, 256, 0, stream>>>(A, offsets, eros, dinv, b1, OUT, N, 1);

    // Layer 2: A = (OUT@W2)*dinv; d_out = gather(A)*dinv + b2
    k_gemm_rowscale<<<nblk, 256, 0, stream>>>(OUT, W2, dinv, A, N, 64);
    k_gather<<<gblk, 256, 0, stream>>>(A, offsets, eros, dinv, b2, OUT, N, 0);
}

// Round 5
// 360.043 us; speedup vs baseline: 1.9752x; 1.9752x over previous
//
#include <hip/hip_runtime.h>

// GCN 2-layer, CSR-gather formulation, bucket-sorted CSR build.
//   out[c] = dinv[c] * ( h_s[c] + sum_{e: col=c} h_s[row_e] ) + b,  h_s=(X@W)*dinv
// CSR build: (A) 782-bucket global histogram (col>>7) + scan; (B) k_bin:
// per-block LDS histogram + ONE cursor atomic per (block,bucket) reservation +
// LDS sort by bucket + run-coalesced global writes of packed (col&127, row);
// (C) per-bucket LDS counting sort -> offsets, dinv, eros (sequential writes).
// Requires N < 2^17 (row packed in 17 bits). Integer inputs arrive as int32.

#define BKT_SH 7            // 128 nodes per bucket
#define BKT_CAP 6144        // max edges per bucket (avg ~2046, +5 sigma ~2275)
#define CHUNK 6144          // edges per k_bin block

__global__ __launch_bounds__(256) void k_zero_i(int* __restrict__ p, int n) {
    int i = blockIdx.x * 256 + threadIdx.x;
    if (i < n) p[i] = 0;
}

// (A1) coarse histogram via per-block LDS hist, merged with global atomics.
__global__ __launch_bounds__(256) void k_bhist(const int* __restrict__ col,
                                               int* __restrict__ bhist,
                                               int nb, int E) {
    __shared__ int h[1024];
    for (int i = threadIdx.x; i < 1024; i += 256) h[i] = 0;
    __syncthreads();
    int stride = gridDim.x * 256;
    for (int i = blockIdx.x * 256 + threadIdx.x; i < E; i += stride)
        atomicAdd(&h[col[i] >> BKT_SH], 1);
    __syncthreads();
    for (int i = threadIdx.x; i < nb; i += 256)
        if (h[i]) atomicAdd(&bhist[i], h[i]);
}

// (A2) single-block exclusive scan of nb (<=1024) bucket counts.
__global__ __launch_bounds__(1024) void k_bscan(const int* __restrict__ bhist,
                                                int* __restrict__ bucket_base,
                                                int* __restrict__ cursor,
                                                int nb, int E) {
    __shared__ int s[1024];
    int t = threadIdx.x;
    int v = (t < nb) ? bhist[t] : 0;
    s[t] = v;
    __syncthreads();
#pragma unroll
    for (int d = 1; d < 1024; d <<= 1) {
        int x = (t >= d) ? s[t - d] : 0;
        __syncthreads();
        if (t >= d) s[t] += x;
        __syncthreads();
    }
    if (t < nb) {
        int ex = s[t] - v;
        bucket_base[t] = ex;
        cursor[t] = ex;
    }
    if (t == 0) bucket_base[nb] = E;
}

// (B) block-chunked binning: LDS hist -> LDS scan -> one reservation atomic
// per (block,bucket) -> LDS sort by bucket -> run-coalesced global writes.
__global__ __launch_bounds__(256) void k_bin(const int* __restrict__ row,
                                             const int* __restrict__ col,
                                             int* __restrict__ cursor,
                                             unsigned* __restrict__ bentries,
                                             int E) {
    __shared__ unsigned sorted[CHUNK];        // 24 KB packed entries, bucket order
    __shared__ unsigned short bof[CHUNK];     // 12 KB bucket of sorted[i]
    __shared__ int hist[1024];
    __shared__ int ex0[1024];
    __shared__ int cur[1024];
    __shared__ int gbase[1024];
    __shared__ int tsum[256];
    int b = blockIdx.x, t = threadIdx.x;
    int s0 = b * CHUNK;
    int cnt = E - s0; if (cnt > CHUNK) cnt = CHUNK;

    for (int i = t; i < 1024; i += 256) hist[i] = 0;
    __syncthreads();
    // pass 1: histogram
    for (int i = t; i < cnt; i += 256)
        atomicAdd(&hist[col[s0 + i] >> BKT_SH], 1);
    __syncthreads();
    // scan 1024 bins: thread t owns bins [4t, 4t+4)
    {
        int b0 = hist[4 * t], b1 = hist[4 * t + 1], b2 = hist[4 * t + 2], b3 = hist[4 * t + 3];
        int tot = b0 + b1 + b2 + b3;
        tsum[t] = tot;
        __syncthreads();
#pragma unroll
        for (int d = 1; d < 256; d <<= 1) {
            int x = (t >= d) ? tsum[t - d] : 0;
            __syncthreads();
            tsum[t] += (t >= d) ? x : 0;
            __syncthreads();
        }
        int ex = tsum[t] - tot;  // exclusive across thread groups
        ex0[4 * t] = ex;
        ex0[4 * t + 1] = ex + b0;
        ex0[4 * t + 2] = ex + b0 + b1;
        ex0[4 * t + 3] = ex + b0 + b1 + b2;
        cur[4 * t] = ex0[4 * t];
        cur[4 * t + 1] = ex0[4 * t + 1];
        cur[4 * t + 2] = ex0[4 * t + 2];
        cur[4 * t + 3] = ex0[4 * t + 3];
    }
    __syncthreads();
    // reserve global ranges: one atomic per non-empty (block,bucket)
    for (int i = t; i < 1024; i += 256)
        if (hist[i] > 0) gbase[i] = atomicAdd(&cursor[i], hist[i]);
    // pass 2: LDS sort by bucket (order within bucket irrelevant)
    for (int i = t; i < cnt; i += 256) {
        int c = col[s0 + i], r = row[s0 + i];
        int bkt = c >> BKT_SH;
        int p = atomicAdd(&cur[bkt], 1);
        sorted[p] = ((unsigned)(c & ((1 << BKT_SH) - 1)) << 17) | (unsigned)r;
        bof[p] = (unsigned short)bkt;
    }
    __syncthreads();
    // pass 3: run-coalesced global writes
    for (int i = t; i < cnt; i += 256) {
        int bkt = bof[i];
        bentries[gbase[bkt] + (i - ex0[bkt])] = sorted[i];
    }
}

// (C) per-bucket counting sort: offsets, dinv, eros (all sequential writes).
__global__ __launch_bounds__(256) void k_bucket_sort(
    const unsigned* __restrict__ bentries, const int* __restrict__ bucket_base,
    int* __restrict__ offsets, float* __restrict__ dinv,
    int* __restrict__ eros, int N, int E) {
    __shared__ int hist[128];
    __shared__ int incl[128];
    __shared__ int cur[128];
    __shared__ int rows[BKT_CAP];
    int b = blockIdx.x, t = threadIdx.x;
    int base = bucket_base[b];
    int cnt = bucket_base[b + 1] - base;
    if (cnt > BKT_CAP) cnt = BKT_CAP;  // safety clamp (never expected)

    if (t < 128) hist[t] = 0;
    __syncthreads();
    for (int i = t; i < cnt; i += 256)
        atomicAdd(&hist[bentries[base + i] >> 17], 1);
    __syncthreads();
    if (t < 128) incl[t] = hist[t];
    __syncthreads();
#pragma unroll
    for (int d = 1; d < 128; d <<= 1) {
        int x = (t < 128 && t >= d) ? incl[t - d] : 0;
        __syncthreads();
        if (t < 128 && t >= d) incl[t] += x;
        __syncthreads();
    }
    if (t < 128) {
        int ex = incl[t] - hist[t];  // exclusive within bucket
        int node = (b << BKT_SH) + t;
        if (node <= N) offsets[node] = base + ex;  // node==N lands on E
        if (node < N) dinv[node] = rsqrtf((float)hist[t] + 1.0f);
        cur[t] = ex;
    }
    __syncthreads();
    for (int i = t; i < cnt; i += 256) {
        unsigned en = bentries[base + i];
        int p = atomicAdd(&cur[en >> 17], 1);
        rows[p] = (int)(en & 0x1FFFF);
    }
    __syncthreads();
    for (int i = t; i < cnt; i += 256) eros[base + i] = rows[i];
}

// out[i][c] = (sum_k X[i][k] * W[k][c]) * dinv[i],  c in [0,64). K = 128 or 64.
// One thread per row, 64 fp32 accumulators, W staged in LDS (<=32 KB).
__global__ __launch_bounds__(256) void k_gemm_rowscale(
    const float* __restrict__ X, const float* __restrict__ W,
    const float* __restrict__ dinv, float* __restrict__ out, int N, int K) {
    __shared__ float w_lds[128 * 64];
    int tid = threadIdx.x;
    int nv4 = K * 16;
    for (int i = tid; i < nv4; i += 256)
        ((float4*)w_lds)[i] = ((const float4*)W)[i];
    __syncthreads();
    int row = blockIdx.x * 256 + tid;
    if (row >= N) return;

    float acc[64];
#pragma unroll
    for (int c = 0; c < 64; ++c) acc[c] = 0.f;

    const float4* xr = (const float4*)(X + (size_t)row * K);
    int K4 = K >> 2;
    for (int k4 = 0; k4 < K4; ++k4) {
        float4 xv = xr[k4];
        const float* wk = w_lds + (k4 << 8);
#pragma unroll
        for (int kk = 0; kk < 4; ++kk) {
            float xk = kk == 0 ? xv.x : kk == 1 ? xv.y : kk == 2 ? xv.z : xv.w;
            const float4* wrow = (const float4*)(wk + kk * 64);
#pragma unroll
            for (int c4 = 0; c4 < 16; ++c4) {
                float4 w = wrow[c4];
                acc[c4 * 4 + 0] = fmaf(xk, w.x, acc[c4 * 4 + 0]);
                acc[c4 * 4 + 1] = fmaf(xk, w.y, acc[c4 * 4 + 1]);
                acc[c4 * 4 + 2] = fmaf(xk, w.z, acc[c4 * 4 + 2]);
                acc[c4 * 4 + 3] = fmaf(xk, w.w, acc[c4 * 4 + 3]);
            }
        }
    }
    float s = dinv[row];
    float4* o = (float4*)(out + (size_t)row * 64);
#pragma unroll
    for (int c4 = 0; c4 < 16; ++c4) {
        float4 v;
        v.x = acc[c4 * 4 + 0] * s;
        v.y = acc[c4 * 4 + 1] * s;
        v.z = acc[c4 * 4 + 2] * s;
        v.w = acc[c4 * 4 + 3] * s;
        o[c4] = v;
    }
}

// Gather-aggregate + fused postproc. One 16-lane group per node; lane l owns
// channels [4l, 4l+4). acc init = src[node] (self loop). No atomics.
__global__ __launch_bounds__(256) void k_gather(
    const float* __restrict__ src, const int* __restrict__ offsets,
    const int* __restrict__ eros, const float* __restrict__ dinv,
    const float* __restrict__ bias, float* __restrict__ dst, int N, int do_relu) {
    int idx = blockIdx.x * 256 + threadIdx.x;
    int node = idx >> 4;
    if (node >= N) return;
    int l = idx & 15;

    const float4* s4 = (const float4*)src;
    float4 acc = s4[(size_t)node * 16 + l];  // self loop
    int e = offsets[node], eend = offsets[node + 1];
    for (; e < eend; ++e) {
        int r = eros[e];
        float4 v = s4[(size_t)r * 16 + l];
        acc.x += v.x; acc.y += v.y; acc.z += v.z; acc.w += v.w;
    }
    float sc = dinv[node];
    float4 b = ((const float4*)bias)[l];
    acc.x = acc.x * sc + b.x;
    acc.y = acc.y * sc + b.y;
    acc.z = acc.z * sc + b.z;
    acc.w = acc.w * sc + b.w;
    if (do_relu) {
        acc.x = fmaxf(acc.x, 0.f);
        acc.y = fmaxf(acc.y, 0.f);
        acc.z = fmaxf(acc.z, 0.f);
        acc.w = fmaxf(acc.w, 0.f);
    }
    ((float4*)dst)[(size_t)node * 16 + l] = acc;
}

extern "C" void kernel_launch(void* const* d_in, const int* in_sizes, int n_in,
                              void* d_out, int out_size, void* d_ws, size_t ws_size,
                              hipStream_t stream) {
    const float* x = (const float*)d_in[0];
    const int* ei = (const int*)d_in[1];  // int32 per harness contract, [2, E]
    const float* W1 = (const float*)d_in[2];
    const float* b1 = (const float*)d_in[3];
    const float* W2 = (const float*)d_in[4];
    const float* b2 = (const float*)d_in[5];

    int N = in_sizes[0] / 128;  // 100000
    int E = in_sizes[1] / 2;    // 1600000
    const int* row = ei;
    const int* col = ei + E;
    int nb = (N + (1 << BKT_SH) - 1) >> BKT_SH;  // 782 buckets

    char* ws = (char*)d_ws;
    int* bhist = (int*)ws;                          // <=1024 ints @ 0
    int* bucket_base = (int*)(ws + (1 << 14));      // <=1025 ints @ 16 KB
    int* cursor = (int*)(ws + (1 << 15));           // <=1024 ints @ 32 KB
    int* offsets = (int*)(ws + (1 << 16));          // N+1 ints @ 64 KB
    float* dinv = (float*)(ws + 576 * 1024);        // N floats @ 576 KB
    // bentries (6.4 MB) overlaps A's region: dead before A is first written.
    unsigned* bentries = (unsigned*)(ws + (2 << 20));  // E u32 @ 2 MB
    float* A = (float*)(ws + (2 << 20));            // N*64 floats @ 2 MB (25.6 MB)
    int* eros = (int*)(ws + (28 << 20));            // E ints @ 28 MB (6.4 MB)
    float* OUT = (float*)d_out;                     // N*64 floats, 2nd buffer

    int nblk = (N + 255) / 256;
    int binblk = (E + CHUNK - 1) / CHUNK;  // 261

    // --- CSR build (bucket sort; once, shared by both layers) ---
    k_zero_i<<<(nb + 255) / 256, 256, 0, stream>>>(bhist, nb);
    k_bhist<<<320, 256, 0, stream>>>(col, bhist, nb, E);
    k_bscan<<<1, 1024, 0, stream>>>(bhist, bucket_base, cursor, nb, E);
    k_bin<<<binblk, 256, 0, stream>>>(row, col, cursor, bentries, E);
    k_bucket_sort<<<nb, 256, 0, stream>>>(bentries, bucket_base, offsets, dinv,
                                          eros, N, E);

    int gblk = (N * 16 + 255) / 256;

    // Layer 1: A = (X@W1)*dinv; OUT = relu(gather(A)*dinv + b1)
    k_gemm_rowscale<<<nblk, 256, 0, stream>>>(x, W1, dinv, A, N, 128);
    k_gather<<<gblk, 256, 0, stream>>>(A, offsets, eros, dinv, b1, OUT, N, 1);

    // Layer 2: A = (OUT@W2)*dinv; d_out = gather(A)*dinv + b2
    k_gemm_rowscale<<<nblk, 256, 0, stream>>>(OUT, W2, dinv, A, N, 64);
    k_gather<<<gblk, 256, 0, stream>>>(A, offsets, eros, dinv, b2, OUT, N, 0);
}

// Round 6
// 345.595 us; speedup vs baseline: 2.0577x; 1.0418x over previous
//
#include <hip/hip_runtime.h>

// GCN 2-layer, CSR-gather formulation, bucket-sorted CSR build.
//   out[c] = dinv[c] * ( h_s[c] + sum_{e: col=c} h_s[row_e] ) + b,  h_s=(X@W)*dinv
// CSR build: (A) 782-bucket global histogram (col>>7) + scan; (B) k_bin:
// per-block LDS histogram + ONE cursor atomic per (block,bucket) reservation +
// LDS sort by bucket + run-coalesced global writes of packed (col&127, row);
// (C) per-bucket LDS counting sort -> offsets, dinv, eros (sequential writes).
// Gather is MLP-unrolled x4 (R5 profile: VGPR=12, serialized ~300cyc chain).
// GEMM does 2 rows/thread (LDS-BW-bound: W reads amortized over 2 rows).
// Requires N < 2^17 (row packed in 17 bits). Integer inputs arrive as int32.

#define BKT_SH 7            // 128 nodes per bucket
#define BKT_CAP 6144        // max edges per bucket (avg ~2046, +5 sigma ~2275)
#define CHUNK 6144          // edges per k_bin block

__global__ __launch_bounds__(256) void k_zero_i(int* __restrict__ p, int n) {
    int i = blockIdx.x * 256 + threadIdx.x;
    if (i < n) p[i] = 0;
}

// (A1) coarse histogram via per-block LDS hist, merged with global atomics.
__global__ __launch_bounds__(256) void k_bhist(const int* __restrict__ col,
                                               int* __restrict__ bhist,
                                               int nb, int E) {
    __shared__ int h[1024];
    for (int i = threadIdx.x; i < 1024; i += 256) h[i] = 0;
    __syncthreads();
    int stride = gridDim.x * 256;
    for (int i = blockIdx.x * 256 + threadIdx.x; i < E; i += stride)
        atomicAdd(&h[col[i] >> BKT_SH], 1);
    __syncthreads();
    for (int i = threadIdx.x; i < nb; i += 256)
        if (h[i]) atomicAdd(&bhist[i], h[i]);
}

// (A2) single-block exclusive scan of nb (<=1024) bucket counts.
__global__ __launch_bounds__(1024) void k_bscan(const int* __restrict__ bhist,
                                                int* __restrict__ bucket_base,
                                                int* __restrict__ cursor,
                                                int nb, int E) {
    __shared__ int s[1024];
    int t = threadIdx.x;
    int v = (t < nb) ? bhist[t] : 0;
    s[t] = v;
    __syncthreads();
#pragma unroll
    for (int d = 1; d < 1024; d <<= 1) {
        int x = (t >= d) ? s[t - d] : 0;
        __syncthreads();
        if (t >= d) s[t] += x;
        __syncthreads();
    }
    if (t < nb) {
        int ex = s[t] - v;
        bucket_base[t] = ex;
        cursor[t] = ex;
    }
    if (t == 0) bucket_base[nb] = E;
}

// (B) block-chunked binning: LDS hist -> LDS scan -> one reservation atomic
// per (block,bucket) -> LDS sort by bucket -> run-coalesced global writes.
__global__ __launch_bounds__(256) void k_bin(const int* __restrict__ row,
                                             const int* __restrict__ col,
                                             int* __restrict__ cursor,
                                             unsigned* __restrict__ bentries,
                                             int E) {
    __shared__ unsigned sorted[CHUNK];        // 24 KB packed entries, bucket order
    __shared__ unsigned short bof[CHUNK];     // 12 KB bucket of sorted[i]
    __shared__ int hist[1024];
    __shared__ int ex0[1024];
    __shared__ int cur[1024];
    __shared__ int gbase[1024];
    __shared__ int tsum[256];
    int b = blockIdx.x, t = threadIdx.x;
    int s0 = b * CHUNK;
    int cnt = E - s0; if (cnt > CHUNK) cnt = CHUNK;

    for (int i = t; i < 1024; i += 256) hist[i] = 0;
    __syncthreads();
    // pass 1: histogram
    for (int i = t; i < cnt; i += 256)
        atomicAdd(&hist[col[s0 + i] >> BKT_SH], 1);
    __syncthreads();
    // scan 1024 bins: thread t owns bins [4t, 4t+4)
    {
        int b0 = hist[4 * t], b1 = hist[4 * t + 1], b2 = hist[4 * t + 2], b3 = hist[4 * t + 3];
        int tot = b0 + b1 + b2 + b3;
        tsum[t] = tot;
        __syncthreads();
#pragma unroll
        for (int d = 1; d < 256; d <<= 1) {
            int x = (t >= d) ? tsum[t - d] : 0;
            __syncthreads();
            tsum[t] += (t >= d) ? x : 0;
            __syncthreads();
        }
        int ex = tsum[t] - tot;  // exclusive across thread groups
        ex0[4 * t] = ex;
        ex0[4 * t + 1] = ex + b0;
        ex0[4 * t + 2] = ex + b0 + b1;
        ex0[4 * t + 3] = ex + b0 + b1 + b2;
        cur[4 * t] = ex0[4 * t];
        cur[4 * t + 1] = ex0[4 * t + 1];
        cur[4 * t + 2] = ex0[4 * t + 2];
        cur[4 * t + 3] = ex0[4 * t + 3];
    }
    __syncthreads();
    // reserve global ranges: one atomic per non-empty (block,bucket)
    for (int i = t; i < 1024; i += 256)
        if (hist[i] > 0) gbase[i] = atomicAdd(&cursor[i], hist[i]);
    // pass 2: LDS sort by bucket (order within bucket irrelevant)
    for (int i = t; i < cnt; i += 256) {
        int c = col[s0 + i], r = row[s0 + i];
        int bkt = c >> BKT_SH;
        int p = atomicAdd(&cur[bkt], 1);
        sorted[p] = ((unsigned)(c & ((1 << BKT_SH) - 1)) << 17) | (unsigned)r;
        bof[p] = (unsigned short)bkt;
    }
    __syncthreads();
    // pass 3: run-coalesced global writes
    for (int i = t; i < cnt; i += 256) {
        int bkt = bof[i];
        bentries[gbase[bkt] + (i - ex0[bkt])] = sorted[i];
    }
}

// (C) per-bucket counting sort: offsets, dinv, eros (all sequential writes).
__global__ __launch_bounds__(256) void k_bucket_sort(
    const unsigned* __restrict__ bentries, const int* __restrict__ bucket_base,
    int* __restrict__ offsets, float* __restrict__ dinv,
    int* __restrict__ eros, int N, int E) {
    __shared__ int hist[128];
    __shared__ int incl[128];
    __shared__ int cur[128];
    __shared__ int rows[BKT_CAP];
    int b = blockIdx.x, t = threadIdx.x;
    int base = bucket_base[b];
    int cnt = bucket_base[b + 1] - base;
    if (cnt > BKT_CAP) cnt = BKT_CAP;  // safety clamp (never expected)

    if (t < 128) hist[t] = 0;
    __syncthreads();
    for (int i = t; i < cnt; i += 256)
        atomicAdd(&hist[bentries[base + i] >> 17], 1);
    __syncthreads();
    if (t < 128) incl[t] = hist[t];
    __syncthreads();
#pragma unroll
    for (int d = 1; d < 128; d <<= 1) {
        int x = (t < 128 && t >= d) ? incl[t - d] : 0;
        __syncthreads();
        if (t < 128 && t >= d) incl[t] += x;
        __syncthreads();
    }
    if (t < 128) {
        int ex = incl[t] - hist[t];  // exclusive within bucket
        int node = (b << BKT_SH) + t;
        if (node <= N) offsets[node] = base + ex;  // node==N lands on E
        if (node < N) dinv[node] = rsqrtf((float)hist[t] + 1.0f);
        cur[t] = ex;
    }
    __syncthreads();
    for (int i = t; i < cnt; i += 256) {
        unsigned en = bentries[base + i];
        int p = atomicAdd(&cur[en >> 17], 1);
        rows[p] = (int)(en & 0x1FFFF);
    }
    __syncthreads();
    for (int i = t; i < cnt; i += 256) eros[base + i] = rows[i];
}

// out[i][c] = (sum_k X[i][k] * W[k][c]) * dinv[i],  c in [0,64). K = 128 or 64.
// 2 rows per thread (W LDS reads amortized), 2x64 fp32 accumulators.
__global__ __launch_bounds__(256) void k_gemm_rowscale(
    const float* __restrict__ X, const float* __restrict__ W,
    const float* __restrict__ dinv, float* __restrict__ out, int N, int K) {
    __shared__ float w_lds[128 * 64];
    int tid = threadIdx.x;
    int nv4 = K * 16;
    for (int i = tid; i < nv4; i += 256)
        ((float4*)w_lds)[i] = ((const float4*)W)[i];
    __syncthreads();
    int row0 = blockIdx.x * 512 + tid;
    int row1 = row0 + 256;
    bool v0 = row0 < N, v1 = row1 < N;
    if (!v0) return;  // row1 >= N too

    float acc0[64], acc1[64];
#pragma unroll
    for (int c = 0; c < 64; ++c) { acc0[c] = 0.f; acc1[c] = 0.f; }

    const float4* xr0 = (const float4*)(X + (size_t)row0 * K);
    const float4* xr1 = (const float4*)(X + (size_t)row1 * K);
    int K4 = K >> 2;
    for (int k4 = 0; k4 < K4; ++k4) {
        float4 xv0 = xr0[k4];
        float4 xv1 = v1 ? xr1[k4] : make_float4(0.f, 0.f, 0.f, 0.f);
        const float* wk = w_lds + (k4 << 8);
#pragma unroll
        for (int kk = 0; kk < 4; ++kk) {
            float xk0 = kk == 0 ? xv0.x : kk == 1 ? xv0.y : kk == 2 ? xv0.z : xv0.w;
            float xk1 = kk == 0 ? xv1.x : kk == 1 ? xv1.y : kk == 2 ? xv1.z : xv1.w;
            const float4* wrow = (const float4*)(wk + kk * 64);
#pragma unroll
            for (int c4 = 0; c4 < 16; ++c4) {
                float4 w = wrow[c4];
                acc0[c4 * 4 + 0] = fmaf(xk0, w.x, acc0[c4 * 4 + 0]);
                acc0[c4 * 4 + 1] = fmaf(xk0, w.y, acc0[c4 * 4 + 1]);
                acc0[c4 * 4 + 2] = fmaf(xk0, w.z, acc0[c4 * 4 + 2]);
                acc0[c4 * 4 + 3] = fmaf(xk0, w.w, acc0[c4 * 4 + 3]);
                acc1[c4 * 4 + 0] = fmaf(xk1, w.x, acc1[c4 * 4 + 0]);
                acc1[c4 * 4 + 1] = fmaf(xk1, w.y, acc1[c4 * 4 + 1]);
                acc1[c4 * 4 + 2] = fmaf(xk1, w.z, acc1[c4 * 4 + 2]);
                acc1[c4 * 4 + 3] = fmaf(xk1, w.w, acc1[c4 * 4 + 3]);
            }
        }
    }
    float s0 = dinv[row0];
    float4* o0 = (float4*)(out + (size_t)row0 * 64);
#pragma unroll
    for (int c4 = 0; c4 < 16; ++c4) {
        float4 v;
        v.x = acc0[c4 * 4 + 0] * s0;
        v.y = acc0[c4 * 4 + 1] * s0;
        v.z = acc0[c4 * 4 + 2] * s0;
        v.w = acc0[c4 * 4 + 3] * s0;
        o0[c4] = v;
    }
    if (v1) {
        float s1 = dinv[row1];
        float4* o1 = (float4*)(out + (size_t)row1 * 64);
#pragma unroll
        for (int c4 = 0; c4 < 16; ++c4) {
            float4 v;
            v.x = acc1[c4 * 4 + 0] * s1;
            v.y = acc1[c4 * 4 + 1] * s1;
            v.z = acc1[c4 * 4 + 2] * s1;
            v.w = acc1[c4 * 4 + 3] * s1;
            o1[c4] = v;
        }
    }
}

// Gather-aggregate + fused postproc. One 16-lane group per node; lane l owns
// channels [4l, 4l+4). acc init = src[node] (self loop). No atomics.
// Unrolled x4: 4 independent eros loads then 4 independent gathers (MLP).
__global__ __launch_bounds__(256) void k_gather(
    const float* __restrict__ src, const int* __restrict__ offsets,
    const int* __restrict__ eros, const float* __restrict__ dinv,
    const float* __restrict__ bias, float* __restrict__ dst, int N, int do_relu) {
    int idx = blockIdx.x * 256 + threadIdx.x;
    int node = idx >> 4;
    if (node >= N) return;
    int l = idx & 15;

    const float4* s4 = (const float4*)src;
    float4 acc = s4[(size_t)node * 16 + l];  // self loop
    int e = offsets[node], eend = offsets[node + 1];
    for (; e + 4 <= eend; e += 4) {
        int r0 = eros[e + 0];
        int r1 = eros[e + 1];
        int r2 = eros[e + 2];
        int r3 = eros[e + 3];
        float4 v0 = s4[(size_t)r0 * 16 + l];
        float4 v1 = s4[(size_t)r1 * 16 + l];
        float4 v2 = s4[(size_t)r2 * 16 + l];
        float4 v3 = s4[(size_t)r3 * 16 + l];
        acc.x += (v0.x + v1.x) + (v2.x + v3.x);
        acc.y += (v0.y + v1.y) + (v2.y + v3.y);
        acc.z += (v0.z + v1.z) + (v2.z + v3.z);
        acc.w += (v0.w + v1.w) + (v2.w + v3.w);
    }
    for (; e < eend; ++e) {
        int r = eros[e];
        float4 v = s4[(size_t)r * 16 + l];
        acc.x += v.x; acc.y += v.y; acc.z += v.z; acc.w += v.w;
    }
    float sc = dinv[node];
    float4 b = ((const float4*)bias)[l];
    acc.x = acc.x * sc + b.x;
    acc.y = acc.y * sc + b.y;
    acc.z = acc.z * sc + b.z;
    acc.w = acc.w * sc + b.w;
    if (do_relu) {
        acc.x = fmaxf(acc.x, 0.f);
        acc.y = fmaxf(acc.y, 0.f);
        acc.z = fmaxf(acc.z, 0.f);
        acc.w = fmaxf(acc.w, 0.f);
    }
    ((float4*)dst)[(size_t)node * 16 + l] = acc;
}

extern "C" void kernel_launch(void* const* d_in, const int* in_sizes, int n_in,
                              void* d_out, int out_size, void* d_ws, size_t ws_size,
                              hipStream_t stream) {
    const float* x = (const float*)d_in[0];
    const int* ei = (const int*)d_in[1];  // int32 per harness contract, [2, E]
    const float* W1 = (const float*)d_in[2];
    const float* b1 = (const float*)d_in[3];
    const float* W2 = (const float*)d_in[4];
    const float* b2 = (const float*)d_in[5];

    int N = in_sizes[0] / 128;  // 100000
    int E = in_sizes[1] / 2;    // 1600000
    const int* row = ei;
    const int* col = ei + E;
    int nb = (N + (1 << BKT_SH) - 1) >> BKT_SH;  // 782 buckets

    char* ws = (char*)d_ws;
    int* bhist = (int*)ws;                          // <=1024 ints @ 0
    int* bucket_base = (int*)(ws + (1 << 14));      // <=1025 ints @ 16 KB
    int* cursor = (int*)(ws + (1 << 15));           // <=1024 ints @ 32 KB
    int* offsets = (int*)(ws + (1 << 16));          // N+1 ints @ 64 KB
    float* dinv = (float*)(ws + 576 * 1024);        // N floats @ 576 KB
    // bentries (6.4 MB) overlaps A's region: dead before A is first written.
    unsigned* bentries = (unsigned*)(ws + (2 << 20));  // E u32 @ 2 MB
    float* A = (float*)(ws + (2 << 20));            // N*64 floats @ 2 MB (25.6 MB)
    int* eros = (int*)(ws + (28 << 20));            // E ints @ 28 MB (6.4 MB)
    float* OUT = (float*)d_out;                     // N*64 floats, 2nd buffer

    int gemmblk = (N + 511) / 512;
    int binblk = (E + CHUNK - 1) / CHUNK;  // 261

    // --- CSR build (bucket sort; once, shared by both layers) ---
    k_zero_i<<<(nb + 255) / 256, 256, 0, stream>>>(bhist, nb);
    k_bhist<<<320, 256, 0, stream>>>(col, bhist, nb, E);
    k_bscan<<<1, 1024, 0, stream>>>(bhist, bucket_base, cursor, nb, E);
    k_bin<<<binblk, 256, 0, stream>>>(row, col, cursor, bentries, E);
    k_bucket_sort<<<nb, 256, 0, stream>>>(bentries, bucket_base, offsets, dinv,
                                          eros, N, E);

    int gblk = (N * 16 + 255) / 256;

    // Layer 1: A = (X@W1)*dinv; OUT = relu(gather(A)*dinv + b1)
    k_gemm_rowscale<<<gemmblk, 256, 0, stream>>>(x, W1, dinv, A, N, 128);
    k_gather<<<gblk, 256, 0, stream>>>(A, offsets, eros, dinv, b1, OUT, N, 1);

    // Layer 2: A = (OUT@W2)*dinv; d_out = gather(A)*dinv + b2
    k_gemm_rowscale<<<gemmblk, 256, 0, stream>>>(OUT, W2, dinv, A, N, 64);
    k_gather<<<gblk, 256, 0, stream>>>(A, offsets, eros, dinv, b2, OUT, N, 0);
}

// Round 7
// 340.741 us; speedup vs baseline: 2.0871x; 1.0142x over previous
//
#include <hip/hip_runtime.h>

// GCN 2-layer, CSR-gather formulation, bucket-sorted CSR build.
//   out[c] = dinv[c] * ( h_s[c] + sum_{e: col=c} h_s[row_e] ) + b,  h_s=(X@W)*dinv
// CSR build: (A) 782-bucket global histogram (col>>7) + scan; (B) k_bin:
// per-block LDS histogram + ONE cursor atomic per (block,bucket) reservation +
// LDS sort by bucket + run-coalesced global writes of packed (col&127, row);
// (C) per-bucket LDS counting sort -> offsets, dinv, eros (sequential writes).
// GEMM: 1 row/thread x 32 cols/block (2 col-halves -> 782 blocks; R6 showed
// 196 blocks = 7% occupancy = grid-bound). Gather: MLP-unrolled x8.
// Requires N < 2^17 (row packed in 17 bits). Integer inputs arrive as int32.

#define BKT_SH 7            // 128 nodes per bucket
#define BKT_CAP 6144        // max edges per bucket (avg ~2046, +5 sigma ~2275)
#define CHUNK 6144          // edges per k_bin block

__global__ __launch_bounds__(256) void k_zero_i(int* __restrict__ p, int n) {
    int i = blockIdx.x * 256 + threadIdx.x;
    if (i < n) p[i] = 0;
}

// (A1) coarse histogram via per-block LDS hist, merged with global atomics.
__global__ __launch_bounds__(256) void k_bhist(const int* __restrict__ col,
                                               int* __restrict__ bhist,
                                               int nb, int E) {
    __shared__ int h[1024];
    for (int i = threadIdx.x; i < 1024; i += 256) h[i] = 0;
    __syncthreads();
    int stride = gridDim.x * 256;
    for (int i = blockIdx.x * 256 + threadIdx.x; i < E; i += stride)
        atomicAdd(&h[col[i] >> BKT_SH], 1);
    __syncthreads();
    for (int i = threadIdx.x; i < nb; i += 256)
        if (h[i]) atomicAdd(&bhist[i], h[i]);
}

// (A2) single-block exclusive scan of nb (<=1024) bucket counts.
__global__ __launch_bounds__(1024) void k_bscan(const int* __restrict__ bhist,
                                                int* __restrict__ bucket_base,
                                                int* __restrict__ cursor,
                                                int nb, int E) {
    __shared__ int s[1024];
    int t = threadIdx.x;
    int v = (t < nb) ? bhist[t] : 0;
    s[t] = v;
    __syncthreads();
#pragma unroll
    for (int d = 1; d < 1024; d <<= 1) {
        int x = (t >= d) ? s[t - d] : 0;
        __syncthreads();
        if (t >= d) s[t] += x;
        __syncthreads();
    }
    if (t < nb) {
        int ex = s[t] - v;
        bucket_base[t] = ex;
        cursor[t] = ex;
    }
    if (t == 0) bucket_base[nb] = E;
}

// (B) block-chunked binning: LDS hist -> LDS scan -> one reservation atomic
// per (block,bucket) -> LDS sort by bucket -> run-coalesced global writes.
__global__ __launch_bounds__(256) void k_bin(const int* __restrict__ row,
                                             const int* __restrict__ col,
                                             int* __restrict__ cursor,
                                             unsigned* __restrict__ bentries,
                                             int E) {
    __shared__ unsigned sorted[CHUNK];        // 24 KB packed entries, bucket order
    __shared__ unsigned short bof[CHUNK];     // 12 KB bucket of sorted[i]
    __shared__ int hist[1024];
    __shared__ int ex0[1024];
    __shared__ int cur[1024];
    __shared__ int gbase[1024];
    __shared__ int tsum[256];
    int b = blockIdx.x, t = threadIdx.x;
    int s0 = b * CHUNK;
    int cnt = E - s0; if (cnt > CHUNK) cnt = CHUNK;

    for (int i = t; i < 1024; i += 256) hist[i] = 0;
    __syncthreads();
    // pass 1: histogram
    for (int i = t; i < cnt; i += 256)
        atomicAdd(&hist[col[s0 + i] >> BKT_SH], 1);
    __syncthreads();
    // scan 1024 bins: thread t owns bins [4t, 4t+4)
    {
        int b0 = hist[4 * t], b1 = hist[4 * t + 1], b2 = hist[4 * t + 2], b3 = hist[4 * t + 3];
        int tot = b0 + b1 + b2 + b3;
        tsum[t] = tot;
        __syncthreads();
#pragma unroll
        for (int d = 1; d < 256; d <<= 1) {
            int x = (t >= d) ? tsum[t - d] : 0;
            __syncthreads();
            tsum[t] += (t >= d) ? x : 0;
            __syncthreads();
        }
        int ex = tsum[t] - tot;  // exclusive across thread groups
        ex0[4 * t] = ex;
        ex0[4 * t + 1] = ex + b0;
        ex0[4 * t + 2] = ex + b0 + b1;
        ex0[4 * t + 3] = ex + b0 + b1 + b2;
        cur[4 * t] = ex0[4 * t];
        cur[4 * t + 1] = ex0[4 * t + 1];
        cur[4 * t + 2] = ex0[4 * t + 2];
        cur[4 * t + 3] = ex0[4 * t + 3];
    }
    __syncthreads();
    // reserve global ranges: one atomic per non-empty (block,bucket)
    for (int i = t; i < 1024; i += 256)
        if (hist[i] > 0) gbase[i] = atomicAdd(&cursor[i], hist[i]);
    // pass 2: LDS sort by bucket (order within bucket irrelevant)
    for (int i = t; i < cnt; i += 256) {
        int c = col[s0 + i], r = row[s0 + i];
        int bkt = c >> BKT_SH;
        int p = atomicAdd(&cur[bkt], 1);
        sorted[p] = ((unsigned)(c & ((1 << BKT_SH) - 1)) << 17) | (unsigned)r;
        bof[p] = (unsigned short)bkt;
    }
    __syncthreads();
    // pass 3: run-coalesced global writes
    for (int i = t; i < cnt; i += 256) {
        int bkt = bof[i];
        bentries[gbase[bkt] + (i - ex0[bkt])] = sorted[i];
    }
}

// (C) per-bucket counting sort: offsets, dinv, eros (all sequential writes).
__global__ __launch_bounds__(256) void k_bucket_sort(
    const unsigned* __restrict__ bentries, const int* __restrict__ bucket_base,
    int* __restrict__ offsets, float* __restrict__ dinv,
    int* __restrict__ eros, int N, int E) {
    __shared__ int hist[128];
    __shared__ int incl[128];
    __shared__ int cur[128];
    __shared__ int rows[BKT_CAP];
    int b = blockIdx.x, t = threadIdx.x;
    int base = bucket_base[b];
    int cnt = bucket_base[b + 1] - base;
    if (cnt > BKT_CAP) cnt = BKT_CAP;  // safety clamp (never expected)

    if (t < 128) hist[t] = 0;
    __syncthreads();
    for (int i = t; i < cnt; i += 256)
        atomicAdd(&hist[bentries[base + i] >> 17], 1);
    __syncthreads();
    if (t < 128) incl[t] = hist[t];
    __syncthreads();
#pragma unroll
    for (int d = 1; d < 128; d <<= 1) {
        int x = (t < 128 && t >= d) ? incl[t - d] : 0;
        __syncthreads();
        if (t < 128 && t >= d) incl[t] += x;
        __syncthreads();
    }
    if (t < 128) {
        int ex = incl[t] - hist[t];  // exclusive within bucket
        int node = (b << BKT_SH) + t;
        if (node <= N) offsets[node] = base + ex;  // node==N lands on E
        if (node < N) dinv[node] = rsqrtf((float)hist[t] + 1.0f);
        cur[t] = ex;
    }
    __syncthreads();
    for (int i = t; i < cnt; i += 256) {
        unsigned en = bentries[base + i];
        int p = atomicAdd(&cur[en >> 17], 1);
        rows[p] = (int)(en & 0x1FFFF);
    }
    __syncthreads();
    for (int i = t; i < cnt; i += 256) eros[base + i] = rows[i];
}

// out[i][cbase+c] = (sum_k X[i][k] * W[k][cbase+c]) * dinv[i], c in [0,32).
// blockIdx.x: bit0 = column half, rest = row block. 1 row/thread, 32 accums,
// W half staged in LDS (16 KB). 782 blocks for N=100K -> ~3 blocks/CU.
__global__ __launch_bounds__(256) void k_gemm_rowscale(
    const float* __restrict__ X, const float* __restrict__ W,
    const float* __restrict__ dinv, float* __restrict__ out, int N, int K) {
    __shared__ float w_lds[128 * 32];
    int tid = threadIdx.x;
    int cbase = (blockIdx.x & 1) << 5;
    int rowblk = blockIdx.x >> 1;
    int nv4 = K * 8;  // float4 count of W half
    for (int i = tid; i < nv4; i += 256) {
        int k = i >> 3, c4 = i & 7;
        ((float4*)w_lds)[i] = ((const float4*)(W + k * 64 + cbase))[c4];
    }
    __syncthreads();
    int row = rowblk * 256 + tid;
    if (row >= N) return;

    float acc[32];
#pragma unroll
    for (int c = 0; c < 32; ++c) acc[c] = 0.f;

    const float4* xr = (const float4*)(X + (size_t)row * K);
    int K4 = K >> 2;
    for (int k4 = 0; k4 < K4; ++k4) {
        float4 xv = xr[k4];
        const float* wk = w_lds + (k4 << 7);  // 4 k-rows of 32
#pragma unroll
        for (int kk = 0; kk < 4; ++kk) {
            float xk = kk == 0 ? xv.x : kk == 1 ? xv.y : kk == 2 ? xv.z : xv.w;
            const float4* wrow = (const float4*)(wk + kk * 32);
#pragma unroll
            for (int c4 = 0; c4 < 8; ++c4) {
                float4 w = wrow[c4];
                acc[c4 * 4 + 0] = fmaf(xk, w.x, acc[c4 * 4 + 0]);
                acc[c4 * 4 + 1] = fmaf(xk, w.y, acc[c4 * 4 + 1]);
                acc[c4 * 4 + 2] = fmaf(xk, w.z, acc[c4 * 4 + 2]);
                acc[c4 * 4 + 3] = fmaf(xk, w.w, acc[c4 * 4 + 3]);
            }
        }
    }
    float s = dinv[row];
    float4* o = (float4*)(out + (size_t)row * 64 + cbase);
#pragma unroll
    for (int c4 = 0; c4 < 8; ++c4) {
        float4 v;
        v.x = acc[c4 * 4 + 0] * s;
        v.y = acc[c4 * 4 + 1] * s;
        v.z = acc[c4 * 4 + 2] * s;
        v.w = acc[c4 * 4 + 3] * s;
        o[c4] = v;
    }
}

// Gather-aggregate + fused postproc. One 16-lane group per node; lane l owns
// channels [4l, 4l+4). acc init = src[node] (self loop). No atomics.
// Unrolled x8: 8 independent eros loads then 8 independent gathers (MLP).
__global__ __launch_bounds__(256) void k_gather(
    const float* __restrict__ src, const int* __restrict__ offsets,
    const int* __restrict__ eros, const float* __restrict__ dinv,
    const float* __restrict__ bias, float* __restrict__ dst, int N, int do_relu) {
    int idx = blockIdx.x * 256 + threadIdx.x;
    int node = idx >> 4;
    if (node >= N) return;
    int l = idx & 15;

    const float4* s4 = (const float4*)src;
    float4 acc = s4[(size_t)node * 16 + l];  // self loop
    int e = offsets[node], eend = offsets[node + 1];
    for (; e + 8 <= eend; e += 8) {
        int r0 = eros[e + 0], r1 = eros[e + 1], r2 = eros[e + 2], r3 = eros[e + 3];
        int r4 = eros[e + 4], r5 = eros[e + 5], r6 = eros[e + 6], r7 = eros[e + 7];
        float4 v0 = s4[(size_t)r0 * 16 + l];
        float4 v1 = s4[(size_t)r1 * 16 + l];
        float4 v2 = s4[(size_t)r2 * 16 + l];
        float4 v3 = s4[(size_t)r3 * 16 + l];
        float4 v4 = s4[(size_t)r4 * 16 + l];
        float4 v5 = s4[(size_t)r5 * 16 + l];
        float4 v6 = s4[(size_t)r6 * 16 + l];
        float4 v7 = s4[(size_t)r7 * 16 + l];
        acc.x += ((v0.x + v1.x) + (v2.x + v3.x)) + ((v4.x + v5.x) + (v6.x + v7.x));
        acc.y += ((v0.y + v1.y) + (v2.y + v3.y)) + ((v4.y + v5.y) + (v6.y + v7.y));
        acc.z += ((v0.z + v1.z) + (v2.z + v3.z)) + ((v4.z + v5.z) + (v6.z + v7.z));
        acc.w += ((v0.w + v1.w) + (v2.w + v3.w)) + ((v4.w + v5.w) + (v6.w + v7.w));
    }
    for (; e + 4 <= eend; e += 4) {
        int r0 = eros[e + 0], r1 = eros[e + 1], r2 = eros[e + 2], r3 = eros[e + 3];
        float4 v0 = s4[(size_t)r0 * 16 + l];
        float4 v1 = s4[(size_t)r1 * 16 + l];
        float4 v2 = s4[(size_t)r2 * 16 + l];
        float4 v3 = s4[(size_t)r3 * 16 + l];
        acc.x += (v0.x + v1.x) + (v2.x + v3.x);
        acc.y += (v0.y + v1.y) + (v2.y + v3.y);
        acc.z += (v0.z + v1.z) + (v2.z + v3.z);
        acc.w += (v0.w + v1.w) + (v2.w + v3.w);
    }
    for (; e < eend; ++e) {
        int r = eros[e];
        float4 v = s4[(size_t)r * 16 + l];
        acc.x += v.x; acc.y += v.y; acc.z += v.z; acc.w += v.w;
    }
    float sc = dinv[node];
    float4 b = ((const float4*)bias)[l];
    acc.x = acc.x * sc + b.x;
    acc.y = acc.y * sc + b.y;
    acc.z = acc.z * sc + b.z;
    acc.w = acc.w * sc + b.w;
    if (do_relu) {
        acc.x = fmaxf(acc.x, 0.f);
        acc.y = fmaxf(acc.y, 0.f);
        acc.z = fmaxf(acc.z, 0.f);
        acc.w = fmaxf(acc.w, 0.f);
    }
    ((float4*)dst)[(size_t)node * 16 + l] = acc;
}

extern "C" void kernel_launch(void* const* d_in, const int* in_sizes, int n_in,
                              void* d_out, int out_size, void* d_ws, size_t ws_size,
                              hipStream_t stream) {
    const float* x = (const float*)d_in[0];
    const int* ei = (const int*)d_in[1];  // int32 per harness contract, [2, E]
    const float* W1 = (const float*)d_in[2];
    const float* b1 = (const float*)d_in[3];
    const float* W2 = (const float*)d_in[4];
    const float* b2 = (const float*)d_in[5];

    int N = in_sizes[0] / 128;  // 100000
    int E = in_sizes[1] / 2;    // 1600000
    const int* row = ei;
    const int* col = ei + E;
    int nb = (N + (1 << BKT_SH) - 1) >> BKT_SH;  // 782 buckets

    char* ws = (char*)d_ws;
    int* bhist = (int*)ws;                          // <=1024 ints @ 0
    int* bucket_base = (int*)(ws + (1 << 14));      // <=1025 ints @ 16 KB
    int* cursor = (int*)(ws + (1 << 15));           // <=1024 ints @ 32 KB
    int* offsets = (int*)(ws + (1 << 16));          // N+1 ints @ 64 KB
    float* dinv = (float*)(ws + 576 * 1024);        // N floats @ 576 KB
    // bentries (6.4 MB) overlaps A's region: dead before A is first written.
    unsigned* bentries = (unsigned*)(ws + (2 << 20));  // E u32 @ 2 MB
    float* A = (float*)(ws + (2 << 20));            // N*64 floats @ 2 MB (25.6 MB)
    int* eros = (int*)(ws + (28 << 20));            // E ints @ 28 MB (6.4 MB)
    float* OUT = (float*)d_out;                     // N*64 floats, 2nd buffer

    int gemmblk = ((N + 255) / 256) * 2;   // 782 (2 column halves)
    int binblk = (E + CHUNK - 1) / CHUNK;  // 261

    // --- CSR build (bucket sort; once, shared by both layers) ---
    k_zero_i<<<(nb + 255) / 256, 256, 0, stream>>>(bhist, nb);
    k_bhist<<<320, 256, 0, stream>>>(col, bhist, nb, E);
    k_bscan<<<1, 1024, 0, stream>>>(bhist, bucket_base, cursor, nb, E);
    k_bin<<<binblk, 256, 0, stream>>>(row, col, cursor, bentries, E);
    k_bucket_sort<<<nb, 256, 0, stream>>>(bentries, bucket_base, offsets, dinv,
                                          eros, N, E);

    int gblk = (N * 16 + 255) / 256;

    // Layer 1: A = (X@W1)*dinv; OUT = relu(gather(A)*dinv + b1)
    k_gemm_rowscale<<<gemmblk, 256, 0, stream>>>(x, W1, dinv, A, N, 128);
    k_gather<<<gblk, 256, 0, stream>>>(A, offsets, eros, dinv, b1, OUT, N, 1);

    // Layer 2: A = (OUT@W2)*dinv; d_out = gather(A)*dinv + b2
    k_gemm_rowscale<<<gemmblk, 256, 0, stream>>>(OUT, W2, dinv, A, N, 64);
    k_gather<<<gblk, 256, 0, stream>>>(A, offsets, eros, dinv, b2, OUT, N, 0);
}

// Round 8
// 310.849 us; speedup vs baseline: 2.2878x; 1.0962x over previous
//
#include <hip/hip_runtime.h>

// GCN 2-layer, CSR-gather formulation, bucket-sorted CSR build.
//   out[c] = dinv[c] * ( h_s[c] + sum_{e: col=c} h_s[row_e] ) + b,  h_s=(X@W)*dinv
// CSR build: (A) 782-bucket global histogram (col>>7) + scan; (B) k_bin:
// per-block LDS histogram + ONE cursor atomic per (block,bucket) reservation +
// LDS sort by bucket + run-coalesced global writes of packed (col&127, row);
// (C) per-bucket LDS counting sort -> offsets, dinv, eros (sequential writes).
// GEMM: 128x64 LDS-tiled (R7 showed row-per-thread is fetch-bound: 64 distinct
// lines/wave-load + L1 thrash -> 194 MB fetch). X read once, coalesced.
// Gather: MLP-unrolled x8. N < 2^17 (row packed in 17 bits). Int inputs = int32.

#define BKT_SH 7            // 128 nodes per bucket
#define BKT_CAP 6144        // max edges per bucket (avg ~2046, +5 sigma ~2275)
#define CHUNK 6144          // edges per k_bin block
#define BM 128
#define BK 32

__global__ __launch_bounds__(256) void k_zero_i(int* __restrict__ p, int n) {
    int i = blockIdx.x * 256 + threadIdx.x;
    if (i < n) p[i] = 0;
}

// (A1) coarse histogram via per-block LDS hist, merged with global atomics.
__global__ __launch_bounds__(256) void k_bhist(const int* __restrict__ col,
                                               int* __restrict__ bhist,
                                               int nb, int E) {
    __shared__ int h[1024];
    for (int i = threadIdx.x; i < 1024; i += 256) h[i] = 0;
    __syncthreads();
    int stride = gridDim.x * 256;
    for (int i = blockIdx.x * 256 + threadIdx.x; i < E; i += stride)
        atomicAdd(&h[col[i] >> BKT_SH], 1);
    __syncthreads();
    for (int i = threadIdx.x; i < nb; i += 256)
        if (h[i]) atomicAdd(&bhist[i], h[i]);
}

// (A2) single-block exclusive scan of nb (<=1024) bucket counts.
__global__ __launch_bounds__(1024) void k_bscan(const int* __restrict__ bhist,
                                                int* __restrict__ bucket_base,
                                                int* __restrict__ cursor,
                                                int nb, int E) {
    __shared__ int s[1024];
    int t = threadIdx.x;
    int v = (t < nb) ? bhist[t] : 0;
    s[t] = v;
    __syncthreads();
#pragma unroll
    for (int d = 1; d < 1024; d <<= 1) {
        int x = (t >= d) ? s[t - d] : 0;
        __syncthreads();
        if (t >= d) s[t] += x;
        __syncthreads();
    }
    if (t < nb) {
        int ex = s[t] - v;
        bucket_base[t] = ex;
        cursor[t] = ex;
    }
    if (t == 0) bucket_base[nb] = E;
}

// (B) block-chunked binning: LDS hist -> LDS scan -> one reservation atomic
// per (block,bucket) -> LDS sort by bucket -> run-coalesced global writes.
__global__ __launch_bounds__(256) void k_bin(const int* __restrict__ row,
                                             const int* __restrict__ col,
                                             int* __restrict__ cursor,
                                             unsigned* __restrict__ bentries,
                                             int E) {
    __shared__ unsigned sorted[CHUNK];        // 24 KB packed entries, bucket order
    __shared__ unsigned short bof[CHUNK];     // 12 KB bucket of sorted[i]
    __shared__ int hist[1024];
    __shared__ int ex0[1024];
    __shared__ int cur[1024];
    __shared__ int gbase[1024];
    __shared__ int tsum[256];
    int b = blockIdx.x, t = threadIdx.x;
    int s0 = b * CHUNK;
    int cnt = E - s0; if (cnt > CHUNK) cnt = CHUNK;

    for (int i = t; i < 1024; i += 256) hist[i] = 0;
    __syncthreads();
    // pass 1: histogram
    for (int i = t; i < cnt; i += 256)
        atomicAdd(&hist[col[s0 + i] >> BKT_SH], 1);
    __syncthreads();
    // scan 1024 bins: thread t owns bins [4t, 4t+4)
    {
        int b0 = hist[4 * t], b1 = hist[4 * t + 1], b2 = hist[4 * t + 2], b3 = hist[4 * t + 3];
        int tot = b0 + b1 + b2 + b3;
        tsum[t] = tot;
        __syncthreads();
#pragma unroll
        for (int d = 1; d < 256; d <<= 1) {
            int x = (t >= d) ? tsum[t - d] : 0;
            __syncthreads();
            tsum[t] += (t >= d) ? x : 0;
            __syncthreads();
        }
        int ex = tsum[t] - tot;  // exclusive across thread groups
        ex0[4 * t] = ex;
        ex0[4 * t + 1] = ex + b0;
        ex0[4 * t + 2] = ex + b0 + b1;
        ex0[4 * t + 3] = ex + b0 + b1 + b2;
        cur[4 * t] = ex0[4 * t];
        cur[4 * t + 1] = ex0[4 * t + 1];
        cur[4 * t + 2] = ex0[4 * t + 2];
        cur[4 * t + 3] = ex0[4 * t + 3];
    }
    __syncthreads();
    // reserve global ranges: one atomic per non-empty (block,bucket)
    for (int i = t; i < 1024; i += 256)
        if (hist[i] > 0) gbase[i] = atomicAdd(&cursor[i], hist[i]);
    // pass 2: LDS sort by bucket (order within bucket irrelevant)
    for (int i = t; i < cnt; i += 256) {
        int c = col[s0 + i], r = row[s0 + i];
        int bkt = c >> BKT_SH;
        int p = atomicAdd(&cur[bkt], 1);
        sorted[p] = ((unsigned)(c & ((1 << BKT_SH) - 1)) << 17) | (unsigned)r;
        bof[p] = (unsigned short)bkt;
    }
    __syncthreads();
    // pass 3: run-coalesced global writes
    for (int i = t; i < cnt; i += 256) {
        int bkt = bof[i];
        bentries[gbase[bkt] + (i - ex0[bkt])] = sorted[i];
    }
}

// (C) per-bucket counting sort: offsets, dinv, eros (all sequential writes).
__global__ __launch_bounds__(256) void k_bucket_sort(
    const unsigned* __restrict__ bentries, const int* __restrict__ bucket_base,
    int* __restrict__ offsets, float* __restrict__ dinv,
    int* __restrict__ eros, int N, int E) {
    __shared__ int hist[128];
    __shared__ int incl[128];
    __shared__ int cur[128];
    __shared__ int rows[BKT_CAP];
    int b = blockIdx.x, t = threadIdx.x;
    int base = bucket_base[b];
    int cnt = bucket_base[b + 1] - base;
    if (cnt > BKT_CAP) cnt = BKT_CAP;  // safety clamp (never expected)

    if (t < 128) hist[t] = 0;
    __syncthreads();
    for (int i = t; i < cnt; i += 256)
        atomicAdd(&hist[bentries[base + i] >> 17], 1);
    __syncthreads();
    if (t < 128) incl[t] = hist[t];
    __syncthreads();
#pragma unroll
    for (int d = 1; d < 128; d <<= 1) {
        int x = (t < 128 && t >= d) ? incl[t - d] : 0;
        __syncthreads();
        if (t < 128 && t >= d) incl[t] += x;
        __syncthreads();
    }
    if (t < 128) {
        int ex = incl[t] - hist[t];  // exclusive within bucket
        int node = (b << BKT_SH) + t;
        if (node <= N) offsets[node] = base + ex;  // node==N lands on E
        if (node < N) dinv[node] = rsqrtf((float)hist[t] + 1.0f);
        cur[t] = ex;
    }
    __syncthreads();
    for (int i = t; i < cnt; i += 256) {
        unsigned en = bentries[base + i];
        int p = atomicAdd(&cur[en >> 17], 1);
        rows[p] = (int)(en & 0x1FFFF);
    }
    __syncthreads();
    for (int i = t; i < cnt; i += 256) eros[base + i] = rows[i];
}

// Tiled GEMM + row scale: out[i][c] = (sum_k X[i][k]*W[k][c]) * dinv[i].
// Block = 256 threads -> BM=128 rows x 64 cols. K chunked by BK=32.
// Xs transposed [k][row] (pad 4: write conflicts <=4-way, reads broadcast),
// Ws [k][64]. Thread (tm=t>>4, tn=t&15) computes rows tm*8..+8, cols tn*4..+4
// via 3 ds_read_b128 + 32 FMA per k. X read once, fully coalesced.
__global__ __launch_bounds__(256) void k_gemm_tile(
    const float* __restrict__ X, const float* __restrict__ W,
    const float* __restrict__ dinv, float* __restrict__ out, int N, int K) {
    __shared__ float Xs[BK][BM + 4];
    __shared__ float Ws[BK][64];
    int t = threadIdx.x;
    int bm = blockIdx.x * BM;
    int tm = t >> 4, tn = t & 15;

    float acc[8][4];
#pragma unroll
    for (int i = 0; i < 8; ++i)
#pragma unroll
        for (int j = 0; j < 4; ++j) acc[i][j] = 0.f;

    for (int kb = 0; kb < K; kb += BK) {
        // load X tile (128 rows x 32 k), transposed store
#pragma unroll
        for (int it = 0; it < 4; ++it) {
            int r = (t >> 3) + 32 * it;       // 0..127
            int grow = bm + r;
            int k4 = t & 7;                   // float4 index within BK
            float4 v = make_float4(0.f, 0.f, 0.f, 0.f);
            if (grow < N) v = *(const float4*)(X + (size_t)grow * K + kb + k4 * 4);
            Xs[k4 * 4 + 0][r] = v.x;
            Xs[k4 * 4 + 1][r] = v.y;
            Xs[k4 * 4 + 2][r] = v.z;
            Xs[k4 * 4 + 3][r] = v.w;
        }
        // load W chunk (32 x 64 contiguous)
#pragma unroll
        for (int it = 0; it < 2; ++it) {
            int idx = t + 256 * it;           // 0..511 float4s
            ((float4*)Ws)[idx] = ((const float4*)(W + (size_t)kb * 64))[idx];
        }
        __syncthreads();
#pragma unroll
        for (int k = 0; k < BK; ++k) {
            float4 xa = *(const float4*)&Xs[k][tm * 8];
            float4 xb = *(const float4*)&Xs[k][tm * 8 + 4];
            float4 w = *(const float4*)&Ws[k][tn * 4];
            float xs[8] = {xa.x, xa.y, xa.z, xa.w, xb.x, xb.y, xb.z, xb.w};
#pragma unroll
            for (int i = 0; i < 8; ++i) {
                acc[i][0] = fmaf(xs[i], w.x, acc[i][0]);
                acc[i][1] = fmaf(xs[i], w.y, acc[i][1]);
                acc[i][2] = fmaf(xs[i], w.z, acc[i][2]);
                acc[i][3] = fmaf(xs[i], w.w, acc[i][3]);
            }
        }
        __syncthreads();
    }
#pragma unroll
    for (int i = 0; i < 8; ++i) {
        int grow = bm + tm * 8 + i;
        if (grow < N) {
            float s = dinv[grow];
            float4 v;
            v.x = acc[i][0] * s;
            v.y = acc[i][1] * s;
            v.z = acc[i][2] * s;
            v.w = acc[i][3] * s;
            *(float4*)(out + (size_t)grow * 64 + tn * 4) = v;
        }
    }
}

// Gather-aggregate + fused postproc. One 16-lane group per node; lane l owns
// channels [4l, 4l+4). acc init = src[node] (self loop). No atomics.
// Unrolled x8: 8 independent eros loads then 8 independent gathers (MLP).
__global__ __launch_bounds__(256) void k_gather(
    const float* __restrict__ src, const int* __restrict__ offsets,
    const int* __restrict__ eros, const float* __restrict__ dinv,
    const float* __restrict__ bias, float* __restrict__ dst, int N, int do_relu) {
    int idx = blockIdx.x * 256 + threadIdx.x;
    int node = idx >> 4;
    if (node >= N) return;
    int l = idx & 15;

    const float4* s4 = (const float4*)src;
    float4 acc = s4[(size_t)node * 16 + l];  // self loop
    int e = offsets[node], eend = offsets[node + 1];
    for (; e + 8 <= eend; e += 8) {
        int r0 = eros[e + 0], r1 = eros[e + 1], r2 = eros[e + 2], r3 = eros[e + 3];
        int r4 = eros[e + 4], r5 = eros[e + 5], r6 = eros[e + 6], r7 = eros[e + 7];
        float4 v0 = s4[(size_t)r0 * 16 + l];
        float4 v1 = s4[(size_t)r1 * 16 + l];
        float4 v2 = s4[(size_t)r2 * 16 + l];
        float4 v3 = s4[(size_t)r3 * 16 + l];
        float4 v4 = s4[(size_t)r4 * 16 + l];
        float4 v5 = s4[(size_t)r5 * 16 + l];
        float4 v6 = s4[(size_t)r6 * 16 + l];
        float4 v7 = s4[(size_t)r7 * 16 + l];
        acc.x += ((v0.x + v1.x) + (v2.x + v3.x)) + ((v4.x + v5.x) + (v6.x + v7.x));
        acc.y += ((v0.y + v1.y) + (v2.y + v3.y)) + ((v4.y + v5.y) + (v6.y + v7.y));
        acc.z += ((v0.z + v1.z) + (v2.z + v3.z)) + ((v4.z + v5.z) + (v6.z + v7.z));
        acc.w += ((v0.w + v1.w) + (v2.w + v3.w)) + ((v4.w + v5.w) + (v6.w + v7.w));
    }
    for (; e + 4 <= eend; e += 4) {
        int r0 = eros[e + 0], r1 = eros[e + 1], r2 = eros[e + 2], r3 = eros[e + 3];
        float4 v0 = s4[(size_t)r0 * 16 + l];
        float4 v1 = s4[(size_t)r1 * 16 + l];
        float4 v2 = s4[(size_t)r2 * 16 + l];
        float4 v3 = s4[(size_t)r3 * 16 + l];
        acc.x += (v0.x + v1.x) + (v2.x + v3.x);
        acc.y += (v0.y + v1.y) + (v2.y + v3.y);
        acc.z += (v0.z + v1.z) + (v2.z + v3.z);
        acc.w += (v0.w + v1.w) + (v2.w + v3.w);
    }
    for (; e < eend; ++e) {
        int r = eros[e];
        float4 v = s4[(size_t)r * 16 + l];
        acc.x += v.x; acc.y += v.y; acc.z += v.z; acc.w += v.w;
    }
    float sc = dinv[node];
    float4 b = ((const float4*)bias)[l];
    acc.x = acc.x * sc + b.x;
    acc.y = acc.y * sc + b.y;
    acc.z = acc.z * sc + b.z;
    acc.w = acc.w * sc + b.w;
    if (do_relu) {
        acc.x = fmaxf(acc.x, 0.f);
        acc.y = fmaxf(acc.y, 0.f);
        acc.z = fmaxf(acc.z, 0.f);
        acc.w = fmaxf(acc.w, 0.f);
    }
    ((float4*)dst)[(size_t)node * 16 + l] = acc;
}

extern "C" void kernel_launch(void* const* d_in, const int* in_sizes, int n_in,
                              void* d_out, int out_size, void* d_ws, size_t ws_size,
                              hipStream_t stream) {
    const float* x = (const float*)d_in[0];
    const int* ei = (const int*)d_in[1];  // int32 per harness contract, [2, E]
    const float* W1 = (const float*)d_in[2];
    const float* b1 = (const float*)d_in[3];
    const float* W2 = (const float*)d_in[4];
    const float* b2 = (const float*)d_in[5];

    int N = in_sizes[0] / 128;  // 100000
    int E = in_sizes[1] / 2;    // 1600000
    const int* row = ei;
    const int* col = ei + E;
    int nb = (N + (1 << BKT_SH) - 1) >> BKT_SH;  // 782 buckets

    char* ws = (char*)d_ws;
    int* bhist = (int*)ws;                          // <=1024 ints @ 0
    int* bucket_base = (int*)(ws + (1 << 14));      // <=1025 ints @ 16 KB
    int* cursor = (int*)(ws + (1 << 15));           // <=1024 ints @ 32 KB
    int* offsets = (int*)(ws + (1 << 16));          // N+1 ints @ 64 KB
    float* dinv = (float*)(ws + 576 * 1024);        // N floats @ 576 KB
    // bentries (6.4 MB) overlaps A's region: dead before A is first written.
    unsigned* bentries = (unsigned*)(ws + (2 << 20));  // E u32 @ 2 MB
    float* A = (float*)(ws + (2 << 20));            // N*64 floats @ 2 MB (25.6 MB)
    int* eros = (int*)(ws + (28 << 20));            // E ints @ 28 MB (6.4 MB)
    float* OUT = (float*)d_out;                     // N*64 floats, 2nd buffer

    int gemmblk = (N + BM - 1) / BM;       // 782
    int binblk = (E + CHUNK - 1) / CHUNK;  // 261

    // --- CSR build (bucket sort; once, shared by both layers) ---
    k_zero_i<<<(nb + 255) / 256, 256, 0, stream>>>(bhist, nb);
    k_bhist<<<320, 256, 0, stream>>>(col, bhist, nb, E);
    k_bscan<<<1, 1024, 0, stream>>>(bhist, bucket_base, cursor, nb, E);
    k_bin<<<binblk, 256, 0, stream>>>(row, col, cursor, bentries, E);
    k_bucket_sort<<<nb, 256, 0, stream>>>(bentries, bucket_base, offsets, dinv,
                                          eros, N, E);

    int gblk = (N * 16 + 255) / 256;

    // Layer 1: A = (X@W1)*dinv; OUT = relu(gather(A)*dinv + b1)
    k_gemm_tile<<<gemmblk, 256, 0, stream>>>(x, W1, dinv, A, N, 128);
    k_gather<<<gblk, 256, 0, stream>>>(A, offsets, eros, dinv, b1, OUT, N, 1);

    // Layer 2: A = (OUT@W2)*dinv; d_out = gather(A)*dinv + b2
    k_gemm_tile<<<gemmblk, 256, 0, stream>>>(OUT, W2, dinv, A, N, 64);
    k_gather<<<gblk, 256, 0, stream>>>(A, offsets, eros, dinv, b2, OUT, N, 0);
}

// Round 9
// 275.874 us; speedup vs baseline: 2.5778x; 1.1268x over previous
//
#include <hip/hip_runtime.h>

// GCN 2-layer, CSR-gather formulation, bucket-sorted CSR build.
//   out[c] = dinv[c] * ( h_s[c] + sum_{e: col=c} h_s[row_e] ) + b,  h_s=(X@W)*dinv
// R9: messages h_s stored as bf16 (12.8 MB) -> compulsory per-XCD fetch halves
// (R8 showed FETCH=189MB ~ 8 XCD x 25.6MB source = compulsory). Accumulation
// stays fp32; gather MLP-unrolled x16. CSR build unchanged from R8.
// Requires N < 2^17. Integer inputs arrive as int32.

#define BKT_SH 7            // 128 nodes per bucket
#define BKT_CAP 6144        // max edges per bucket (avg ~2046, +5 sigma ~2275)
#define CHUNK 6144          // edges per k_bin block
#define BM 128
#define BK 32

__device__ __forceinline__ unsigned short f2bf(float f) {
    unsigned u = __builtin_bit_cast(unsigned, f);
    u = (u + 0x7FFF + ((u >> 16) & 1)) >> 16;  // RNE
    return (unsigned short)u;
}
__device__ __forceinline__ float bf2f(unsigned short h) {
    unsigned u = ((unsigned)h) << 16;
    return __builtin_bit_cast(float, u);
}

__global__ __launch_bounds__(256) void k_zero_i(int* __restrict__ p, int n) {
    int i = blockIdx.x * 256 + threadIdx.x;
    if (i < n) p[i] = 0;
}

// (A1) coarse histogram via per-block LDS hist, merged with global atomics.
__global__ __launch_bounds__(256) void k_bhist(const int* __restrict__ col,
                                               int* __restrict__ bhist,
                                               int nb, int E) {
    __shared__ int h[1024];
    for (int i = threadIdx.x; i < 1024; i += 256) h[i] = 0;
    __syncthreads();
    int stride = gridDim.x * 256;
    for (int i = blockIdx.x * 256 + threadIdx.x; i < E; i += stride)
        atomicAdd(&h[col[i] >> BKT_SH], 1);
    __syncthreads();
    for (int i = threadIdx.x; i < nb; i += 256)
        if (h[i]) atomicAdd(&bhist[i], h[i]);
}

// (A2) single-block exclusive scan of nb (<=1024) bucket counts.
__global__ __launch_bounds__(1024) void k_bscan(const int* __restrict__ bhist,
                                                int* __restrict__ bucket_base,
                                                int* __restrict__ cursor,
                                                int nb, int E) {
    __shared__ int s[1024];
    int t = threadIdx.x;
    int v = (t < nb) ? bhist[t] : 0;
    s[t] = v;
    __syncthreads();
#pragma unroll
    for (int d = 1; d < 1024; d <<= 1) {
        int x = (t >= d) ? s[t - d] : 0;
        __syncthreads();
        if (t >= d) s[t] += x;
        __syncthreads();
    }
    if (t < nb) {
        int ex = s[t] - v;
        bucket_base[t] = ex;
        cursor[t] = ex;
    }
    if (t == 0) bucket_base[nb] = E;
}

// (B) block-chunked binning: LDS hist -> LDS scan -> one reservation atomic
// per (block,bucket) -> LDS sort by bucket -> run-coalesced global writes.
__global__ __launch_bounds__(256) void k_bin(const int* __restrict__ row,
                                             const int* __restrict__ col,
                                             int* __restrict__ cursor,
                                             unsigned* __restrict__ bentries,
                                             int E) {
    __shared__ unsigned sorted[CHUNK];        // 24 KB packed entries, bucket order
    __shared__ unsigned short bof[CHUNK];     // 12 KB bucket of sorted[i]
    __shared__ int hist[1024];
    __shared__ int ex0[1024];
    __shared__ int cur[1024];
    __shared__ int gbase[1024];
    __shared__ int tsum[256];
    int b = blockIdx.x, t = threadIdx.x;
    int s0 = b * CHUNK;
    int cnt = E - s0; if (cnt > CHUNK) cnt = CHUNK;

    for (int i = t; i < 1024; i += 256) hist[i] = 0;
    __syncthreads();
    // pass 1: histogram
    for (int i = t; i < cnt; i += 256)
        atomicAdd(&hist[col[s0 + i] >> BKT_SH], 1);
    __syncthreads();
    // scan 1024 bins: thread t owns bins [4t, 4t+4)
    {
        int b0 = hist[4 * t], b1 = hist[4 * t + 1], b2 = hist[4 * t + 2], b3 = hist[4 * t + 3];
        int tot = b0 + b1 + b2 + b3;
        tsum[t] = tot;
        __syncthreads();
#pragma unroll
        for (int d = 1; d < 256; d <<= 1) {
            int x = (t >= d) ? tsum[t - d] : 0;
            __syncthreads();
            tsum[t] += (t >= d) ? x : 0;
            __syncthreads();
        }
        int ex = tsum[t] - tot;  // exclusive across thread groups
        ex0[4 * t] = ex;
        ex0[4 * t + 1] = ex + b0;
        ex0[4 * t + 2] = ex + b0 + b1;
        ex0[4 * t + 3] = ex + b0 + b1 + b2;
        cur[4 * t] = ex0[4 * t];
        cur[4 * t + 1] = ex0[4 * t + 1];
        cur[4 * t + 2] = ex0[4 * t + 2];
        cur[4 * t + 3] = ex0[4 * t + 3];
    }
    __syncthreads();
    // reserve global ranges: one atomic per non-empty (block,bucket)
    for (int i = t; i < 1024; i += 256)
        if (hist[i] > 0) gbase[i] = atomicAdd(&cursor[i], hist[i]);
    // pass 2: LDS sort by bucket (order within bucket irrelevant)
    for (int i = t; i < cnt; i += 256) {
        int c = col[s0 + i], r = row[s0 + i];
        int bkt = c >> BKT_SH;
        int p = atomicAdd(&cur[bkt], 1);
        sorted[p] = ((unsigned)(c & ((1 << BKT_SH) - 1)) << 17) | (unsigned)r;
        bof[p] = (unsigned short)bkt;
    }
    __syncthreads();
    // pass 3: run-coalesced global writes
    for (int i = t; i < cnt; i += 256) {
        int bkt = bof[i];
        bentries[gbase[bkt] + (i - ex0[bkt])] = sorted[i];
    }
}

// (C) per-bucket counting sort: offsets, dinv, eros (all sequential writes).
__global__ __launch_bounds__(256) void k_bucket_sort(
    const unsigned* __restrict__ bentries, const int* __restrict__ bucket_base,
    int* __restrict__ offsets, float* __restrict__ dinv,
    int* __restrict__ eros, int N, int E) {
    __shared__ int hist[128];
    __shared__ int incl[128];
    __shared__ int cur[128];
    __shared__ int rows[BKT_CAP];
    int b = blockIdx.x, t = threadIdx.x;
    int base = bucket_base[b];
    int cnt = bucket_base[b + 1] - base;
    if (cnt > BKT_CAP) cnt = BKT_CAP;  // safety clamp (never expected)

    if (t < 128) hist[t] = 0;
    __syncthreads();
    for (int i = t; i < cnt; i += 256)
        atomicAdd(&hist[bentries[base + i] >> 17], 1);
    __syncthreads();
    if (t < 128) incl[t] = hist[t];
    __syncthreads();
#pragma unroll
    for (int d = 1; d < 128; d <<= 1) {
        int x = (t < 128 && t >= d) ? incl[t - d] : 0;
        __syncthreads();
        if (t < 128 && t >= d) incl[t] += x;
        __syncthreads();
    }
    if (t < 128) {
        int ex = incl[t] - hist[t];  // exclusive within bucket
        int node = (b << BKT_SH) + t;
        if (node <= N) offsets[node] = base + ex;  // node==N lands on E
        if (node < N) dinv[node] = rsqrtf((float)hist[t] + 1.0f);
        cur[t] = ex;
    }
    __syncthreads();
    for (int i = t; i < cnt; i += 256) {
        unsigned en = bentries[base + i];
        int p = atomicAdd(&cur[en >> 17], 1);
        rows[p] = (int)(en & 0x1FFFF);
    }
    __syncthreads();
    for (int i = t; i < cnt; i += 256) eros[base + i] = rows[i];
}

// Tiled GEMM + row scale, bf16 output: outb[i][c] = bf16((sum_k X[i][k]*W[k][c]) * dinv[i]).
// Block = 256 threads -> BM=128 rows x 64 cols. K chunked by BK=32.
__global__ __launch_bounds__(256) void k_gemm_tile(
    const float* __restrict__ X, const float* __restrict__ W,
    const float* __restrict__ dinv, unsigned short* __restrict__ outb,
    int N, int K) {
    __shared__ float Xs[BK][BM + 4];
    __shared__ float Ws[BK][64];
    int t = threadIdx.x;
    int bm = blockIdx.x * BM;
    int tm = t >> 4, tn = t & 15;

    float acc[8][4];
#pragma unroll
    for (int i = 0; i < 8; ++i)
#pragma unroll
        for (int j = 0; j < 4; ++j) acc[i][j] = 0.f;

    for (int kb = 0; kb < K; kb += BK) {
#pragma unroll
        for (int it = 0; it < 4; ++it) {
            int r = (t >> 3) + 32 * it;       // 0..127
            int grow = bm + r;
            int k4 = t & 7;                   // float4 index within BK
            float4 v = make_float4(0.f, 0.f, 0.f, 0.f);
            if (grow < N) v = *(const float4*)(X + (size_t)grow * K + kb + k4 * 4);
            Xs[k4 * 4 + 0][r] = v.x;
            Xs[k4 * 4 + 1][r] = v.y;
            Xs[k4 * 4 + 2][r] = v.z;
            Xs[k4 * 4 + 3][r] = v.w;
        }
#pragma unroll
        for (int it = 0; it < 2; ++it) {
            int idx = t + 256 * it;           // 0..511 float4s
            ((float4*)Ws)[idx] = ((const float4*)(W + (size_t)kb * 64))[idx];
        }
        __syncthreads();
#pragma unroll
        for (int k = 0; k < BK; ++k) {
            float4 xa = *(const float4*)&Xs[k][tm * 8];
            float4 xb = *(const float4*)&Xs[k][tm * 8 + 4];
            float4 w = *(const float4*)&Ws[k][tn * 4];
            float xs[8] = {xa.x, xa.y, xa.z, xa.w, xb.x, xb.y, xb.z, xb.w};
#pragma unroll
            for (int i = 0; i < 8; ++i) {
                acc[i][0] = fmaf(xs[i], w.x, acc[i][0]);
                acc[i][1] = fmaf(xs[i], w.y, acc[i][1]);
                acc[i][2] = fmaf(xs[i], w.z, acc[i][2]);
                acc[i][3] = fmaf(xs[i], w.w, acc[i][3]);
            }
        }
        __syncthreads();
    }
#pragma unroll
    for (int i = 0; i < 8; ++i) {
        int grow = bm + tm * 8 + i;
        if (grow < N) {
            float s = dinv[grow];
            ushort4 v;
            v.x = f2bf(acc[i][0] * s);
            v.y = f2bf(acc[i][1] * s);
            v.z = f2bf(acc[i][2] * s);
            v.w = f2bf(acc[i][3] * s);
            *(ushort4*)(outb + (size_t)grow * 64 + tn * 4) = v;
        }
    }
}

// Gather-aggregate + fused postproc. One 16-lane group per node; lane l owns
// channels [4l, 4l+4). bf16 messages (8 B/lane/edge), fp32 accumulate.
// acc init = src[node] (self loop). MLP-unrolled x16.
__global__ __launch_bounds__(256) void k_gather(
    const unsigned short* __restrict__ srcb, const int* __restrict__ offsets,
    const int* __restrict__ eros, const float* __restrict__ dinv,
    const float* __restrict__ bias, float* __restrict__ dst, int N, int do_relu) {
    int idx = blockIdx.x * 256 + threadIdx.x;
    int node = idx >> 4;
    if (node >= N) return;
    int l = idx & 15;

    const ushort4* s4 = (const ushort4*)srcb;
    ushort4 sv = s4[(size_t)node * 16 + l];  // self loop
    float ax = bf2f(sv.x), ay = bf2f(sv.y), az = bf2f(sv.z), aw = bf2f(sv.w);
    int e = offsets[node], eend = offsets[node + 1];
    for (; e + 16 <= eend; e += 16) {
        ushort4 v[16];
#pragma unroll
        for (int j = 0; j < 16; ++j) {
            int r = eros[e + j];
            v[j] = s4[(size_t)r * 16 + l];
        }
#pragma unroll
        for (int j = 0; j < 16; ++j) {
            ax += bf2f(v[j].x);
            ay += bf2f(v[j].y);
            az += bf2f(v[j].z);
            aw += bf2f(v[j].w);
        }
    }
    for (; e + 4 <= eend; e += 4) {
        ushort4 v[4];
#pragma unroll
        for (int j = 0; j < 4; ++j) {
            int r = eros[e + j];
            v[j] = s4[(size_t)r * 16 + l];
        }
#pragma unroll
        for (int j = 0; j < 4; ++j) {
            ax += bf2f(v[j].x);
            ay += bf2f(v[j].y);
            az += bf2f(v[j].z);
            aw += bf2f(v[j].w);
        }
    }
    for (; e < eend; ++e) {
        int r = eros[e];
        ushort4 v = s4[(size_t)r * 16 + l];
        ax += bf2f(v.x); ay += bf2f(v.y); az += bf2f(v.z); aw += bf2f(v.w);
    }
    float sc = dinv[node];
    float4 b = ((const float4*)bias)[l];
    float4 o;
    o.x = ax * sc + b.x;
    o.y = ay * sc + b.y;
    o.z = az * sc + b.z;
    o.w = aw * sc + b.w;
    if (do_relu) {
        o.x = fmaxf(o.x, 0.f);
        o.y = fmaxf(o.y, 0.f);
        o.z = fmaxf(o.z, 0.f);
        o.w = fmaxf(o.w, 0.f);
    }
    ((float4*)dst)[(size_t)node * 16 + l] = o;
}

extern "C" void kernel_launch(void* const* d_in, const int* in_sizes, int n_in,
                              void* d_out, int out_size, void* d_ws, size_t ws_size,
                              hipStream_t stream) {
    const float* x = (const float*)d_in[0];
    const int* ei = (const int*)d_in[1];  // int32 per harness contract, [2, E]
    const float* W1 = (const float*)d_in[2];
    const float* b1 = (const float*)d_in[3];
    const float* W2 = (const float*)d_in[4];
    const float* b2 = (const float*)d_in[5];

    int N = in_sizes[0] / 128;  // 100000
    int E = in_sizes[1] / 2;    // 1600000
    const int* row = ei;
    const int* col = ei + E;
    int nb = (N + (1 << BKT_SH) - 1) >> BKT_SH;  // 782 buckets

    char* ws = (char*)d_ws;
    int* bhist = (int*)ws;                          // <=1024 ints @ 0
    int* bucket_base = (int*)(ws + (1 << 14));      // <=1025 ints @ 16 KB
    int* cursor = (int*)(ws + (1 << 15));           // <=1024 ints @ 32 KB
    int* offsets = (int*)(ws + (1 << 16));          // N+1 ints @ 64 KB
    float* dinv = (float*)(ws + 576 * 1024);        // N floats @ 576 KB
    // bentries (6.4 MB) overlaps Ab's region: dead before Ab is first written.
    unsigned* bentries = (unsigned*)(ws + (2 << 20));   // E u32 @ 2 MB
    unsigned short* Ab = (unsigned short*)(ws + (2 << 20));  // N*64 bf16 @ 2 MB (12.8 MB)
    int* eros = (int*)(ws + (28 << 20));            // E ints @ 28 MB (6.4 MB)
    float* OUT = (float*)d_out;                     // N*64 fp32, 2nd buffer

    int gemmblk = (N + BM - 1) / BM;       // 782
    int binblk = (E + CHUNK - 1) / CHUNK;  // 261

    // --- CSR build (bucket sort; once, shared by both layers) ---
    k_zero_i<<<(nb + 255) / 256, 256, 0, stream>>>(bhist, nb);
    k_bhist<<<320, 256, 0, stream>>>(col, bhist, nb, E);
    k_bscan<<<1, 1024, 0, stream>>>(bhist, bucket_base, cursor, nb, E);
    k_bin<<<binblk, 256, 0, stream>>>(row, col, cursor, bentries, E);
    k_bucket_sort<<<nb, 256, 0, stream>>>(bentries, bucket_base, offsets, dinv,
                                          eros, N, E);

    int gblk = (N * 16 + 255) / 256;

    // Layer 1: Ab = bf16((X@W1)*dinv); OUT = relu(gather(Ab)*dinv + b1)
    k_gemm_tile<<<gemmblk, 256, 0, stream>>>(x, W1, dinv, Ab, N, 128);
    k_gather<<<gblk, 256, 0, stream>>>(Ab, offsets, eros, dinv, b1, OUT, N, 1);

    // Layer 2: Ab = bf16((OUT@W2)*dinv); d_out = gather(Ab)*dinv + b2
    k_gemm_tile<<<gemmblk, 256, 0, stream>>>(OUT, W2, dinv, Ab, N, 64);
    k_gather<<<gblk, 256, 0, stream>>>(Ab, offsets, eros, dinv, b2, OUT, N, 0);
}

// Round 10
// 246.041 us; speedup vs baseline: 2.8904x; 1.1213x over previous
//
#include <hip/hip_runtime.h>

// GCN 2-layer, CSR-gather formulation, padded-bucket CSR build.
//   out[c] = dinv[c] * ( h_s[c] + sum_{e: col=c} h_s[row_e] ) + b,  h_s=(X@W)*dinv
// R10: (1) fixed-capacity bucket regions (bkt*CAP) -> no global histogram or
// scan (k_bhist/k_bscan deleted); k_bin reserves via zero-init count cursors.
// (2) k_bucket_sort sorts in-place, emits per-node start/cnt. (3) gather uses
// 8 lanes/node x uint4 (packed bf16), MLP unroll 8. (4) layer boundary h2 in
// bf16 (d_out scratch) -> gemm-2 reads bf16. Messages bf16, accum fp32.
// Requires N < 2^17. Integer inputs arrive as int32.

#define BKT_SH 7            // 128 nodes per bucket
#define BKT_CAP 4096        // region per bucket (counts ~2046 +- 45; huge margin)
#define CHUNK 6144          // edges per k_bin block
#define BM 128
#define BK 32

__device__ __forceinline__ unsigned short f2bf(float f) {
    unsigned u = __builtin_bit_cast(unsigned, f);
    u = (u + 0x7FFF + ((u >> 16) & 1)) >> 16;  // RNE
    return (unsigned short)u;
}
__device__ __forceinline__ float bflo(unsigned u) {  // low bf16 of packed pair
    return __builtin_bit_cast(float, u << 16);
}
__device__ __forceinline__ float bfhi(unsigned u) {  // high bf16 of packed pair
    return __builtin_bit_cast(float, u & 0xFFFF0000u);
}

__global__ __launch_bounds__(256) void k_zero_i(int* __restrict__ p, int n) {
    int i = blockIdx.x * 256 + threadIdx.x;
    if (i < n) p[i] = 0;
}

// (A) block-chunked binning: LDS hist -> LDS scan -> one count-reservation
// atomic per (block,bucket) -> LDS sort by bucket -> run-coalesced writes into
// fixed bucket region [bkt*CAP, (bkt+1)*CAP). cursor zero-init; ends = counts.
__global__ __launch_bounds__(256) void k_bin(const int* __restrict__ row,
                                             const int* __restrict__ col,
                                             int* __restrict__ cursor,
                                             unsigned* __restrict__ bentries,
                                             int E) {
    __shared__ unsigned sorted[CHUNK];        // 24 KB packed entries, bucket order
    __shared__ unsigned short bof[CHUNK];     // 12 KB bucket of sorted[i]
    __shared__ int hist[1024];
    __shared__ int ex0[1024];
    __shared__ int cur[1024];
    __shared__ int gbase[1024];
    __shared__ int tsum[256];
    int b = blockIdx.x, t = threadIdx.x;
    int s0 = b * CHUNK;
    int cnt = E - s0; if (cnt > CHUNK) cnt = CHUNK;

    for (int i = t; i < 1024; i += 256) hist[i] = 0;
    __syncthreads();
    // pass 1: histogram
    for (int i = t; i < cnt; i += 256)
        atomicAdd(&hist[col[s0 + i] >> BKT_SH], 1);
    __syncthreads();
    // scan 1024 bins: thread t owns bins [4t, 4t+4)
    {
        int b0 = hist[4 * t], b1 = hist[4 * t + 1], b2 = hist[4 * t + 2], b3 = hist[4 * t + 3];
        int tot = b0 + b1 + b2 + b3;
        tsum[t] = tot;
        __syncthreads();
#pragma unroll
        for (int d = 1; d < 256; d <<= 1) {
            int x = (t >= d) ? tsum[t - d] : 0;
            __syncthreads();
            tsum[t] += (t >= d) ? x : 0;
            __syncthreads();
        }
        int ex = tsum[t] - tot;  // exclusive across thread groups
        ex0[4 * t] = ex;
        ex0[4 * t + 1] = ex + b0;
        ex0[4 * t + 2] = ex + b0 + b1;
        ex0[4 * t + 3] = ex + b0 + b1 + b2;
        cur[4 * t] = ex0[4 * t];
        cur[4 * t + 1] = ex0[4 * t + 1];
        cur[4 * t + 2] = ex0[4 * t + 2];
        cur[4 * t + 3] = ex0[4 * t + 3];
    }
    __syncthreads();
    // reserve: one atomic per non-empty (block,bucket); region base is fixed
    for (int i = t; i < 1024; i += 256)
        if (hist[i] > 0) gbase[i] = i * BKT_CAP + atomicAdd(&cursor[i], hist[i]);
    // pass 2: LDS sort by bucket (order within bucket irrelevant)
    for (int i = t; i < cnt; i += 256) {
        int c = col[s0 + i], r = row[s0 + i];
        int bkt = c >> BKT_SH;
        int p = atomicAdd(&cur[bkt], 1);
        sorted[p] = ((unsigned)(c & ((1 << BKT_SH) - 1)) << 17) | (unsigned)r;
        bof[p] = (unsigned short)bkt;
    }
    __syncthreads();
    // pass 3: run-coalesced global writes (guard against region overflow)
    for (int i = t; i < cnt; i += 256) {
        int bkt = bof[i];
        int pos = gbase[bkt] + (i - ex0[bkt]);
        if (pos < (bkt + 1) * BKT_CAP) bentries[pos] = sorted[i];
    }
}

// (B) per-bucket counting sort IN PLACE: bentries[b*CAP..] -> row indices
// sorted by destination node; emits start[node], cnt[node], dinv[node].
__global__ __launch_bounds__(256) void k_bucket_sort(
    unsigned* __restrict__ bentries, const int* __restrict__ cursor,
    int* __restrict__ start, int* __restrict__ cntarr,
    float* __restrict__ dinv, int N) {
    __shared__ int hist[128];
    __shared__ int incl[128];
    __shared__ int cur[128];
    __shared__ int rows[BKT_CAP];  // 16 KB
    int b = blockIdx.x, t = threadIdx.x;
    int base = b * BKT_CAP;
    int cnt = cursor[b];
    if (cnt > BKT_CAP) cnt = BKT_CAP;  // safety clamp (never expected)

    if (t < 128) hist[t] = 0;
    __syncthreads();
    for (int i = t; i < cnt; i += 256)
        atomicAdd(&hist[bentries[base + i] >> 17], 1);
    __syncthreads();
    if (t < 128) incl[t] = hist[t];
    __syncthreads();
#pragma unroll
    for (int d = 1; d < 128; d <<= 1) {
        int x = (t < 128 && t >= d) ? incl[t - d] : 0;
        __syncthreads();
        if (t < 128 && t >= d) incl[t] += x;
        __syncthreads();
    }
    if (t < 128) {
        int ex = incl[t] - hist[t];  // exclusive within bucket
        int node = (b << BKT_SH) + t;
        if (node < N) {
            start[node] = base + ex;
            cntarr[node] = hist[t];
            dinv[node] = rsqrtf((float)hist[t] + 1.0f);  // +1 self loop
        }
        cur[t] = ex;
    }
    __syncthreads();
    for (int i = t; i < cnt; i += 256) {
        unsigned en = bentries[base + i];
        int p = atomicAdd(&cur[en >> 17], 1);
        rows[p] = (int)(en & 0x1FFFF);
    }
    __syncthreads();
    for (int i = t; i < cnt; i += 256) bentries[base + i] = (unsigned)rows[i];
}

// Tiled GEMM + row scale, fp32 input, bf16 output.
// Block = 256 threads -> BM=128 rows x 64 cols. K chunked by BK=32.
__global__ __launch_bounds__(256) void k_gemm_f32in(
    const float* __restrict__ X, const float* __restrict__ W,
    const float* __restrict__ dinv, unsigned short* __restrict__ outb,
    int N, int K) {
    __shared__ float Xs[BK][BM + 4];
    __shared__ float Ws[BK][64];
    int t = threadIdx.x;
    int bm = blockIdx.x * BM;
    int tm = t >> 4, tn = t & 15;

    float acc[8][4];
#pragma unroll
    for (int i = 0; i < 8; ++i)
#pragma unroll
        for (int j = 0; j < 4; ++j) acc[i][j] = 0.f;

    for (int kb = 0; kb < K; kb += BK) {
#pragma unroll
        for (int it = 0; it < 4; ++it) {
            int r = (t >> 3) + 32 * it;       // 0..127
            int grow = bm + r;
            int k4 = t & 7;                   // float4 index within BK
            float4 v = make_float4(0.f, 0.f, 0.f, 0.f);
            if (grow < N) v = *(const float4*)(X + (size_t)grow * K + kb + k4 * 4);
            Xs[k4 * 4 + 0][r] = v.x;
            Xs[k4 * 4 + 1][r] = v.y;
            Xs[k4 * 4 + 2][r] = v.z;
            Xs[k4 * 4 + 3][r] = v.w;
        }
#pragma unroll
        for (int it = 0; it < 2; ++it) {
            int idx = t + 256 * it;           // 0..511 float4s
            ((float4*)Ws)[idx] = ((const float4*)(W + (size_t)kb * 64))[idx];
        }
        __syncthreads();
#pragma unroll
        for (int k = 0; k < BK; ++k) {
            float4 xa = *(const float4*)&Xs[k][tm * 8];
            float4 xb = *(const float4*)&Xs[k][tm * 8 + 4];
            float4 w = *(const float4*)&Ws[k][tn * 4];
            float xs[8] = {xa.x, xa.y, xa.z, xa.w, xb.x, xb.y, xb.z, xb.w};
#pragma unroll
            for (int i = 0; i < 8; ++i) {
                acc[i][0] = fmaf(xs[i], w.x, acc[i][0]);
                acc[i][1] = fmaf(xs[i], w.y, acc[i][1]);
                acc[i][2] = fmaf(xs[i], w.z, acc[i][2]);
                acc[i][3] = fmaf(xs[i], w.w, acc[i][3]);
            }
        }
        __syncthreads();
    }
#pragma unroll
    for (int i = 0; i < 8; ++i) {
        int grow = bm + tm * 8 + i;
        if (grow < N) {
            float s = dinv[grow];
            ushort4 v;
            v.x = f2bf(acc[i][0] * s);
            v.y = f2bf(acc[i][1] * s);
            v.z = f2bf(acc[i][2] * s);
            v.w = f2bf(acc[i][3] * s);
            *(ushort4*)(outb + (size_t)grow * 64 + tn * 4) = v;
        }
    }
}

// Tiled GEMM + row scale, bf16 input, bf16 output. Same tile shape.
__global__ __launch_bounds__(256) void k_gemm_bf16in(
    const unsigned short* __restrict__ Xb, const float* __restrict__ W,
    const float* __restrict__ dinv, unsigned short* __restrict__ outb,
    int N, int K) {
    __shared__ float Xs[BK][BM + 4];
    __shared__ float Ws[BK][64];
    int t = threadIdx.x;
    int bm = blockIdx.x * BM;
    int tm = t >> 4, tn = t & 15;

    float acc[8][4];
#pragma unroll
    for (int i = 0; i < 8; ++i)
#pragma unroll
        for (int j = 0; j < 4; ++j) acc[i][j] = 0.f;

    for (int kb = 0; kb < K; kb += BK) {
        // 128 rows x 32 k bf16 = 512 uint4 (8 bf16 each); 2 per thread
#pragma unroll
        for (int it = 0; it < 2; ++it) {
            int idx = t * 2 + it;             // 0..511
            int r = idx >> 2;                 // 0..127
            int q = idx & 3;                  // 16B chunk: k = q*8..q*8+8
            int grow = bm + r;
            uint4 v = make_uint4(0u, 0u, 0u, 0u);
            if (grow < N) v = *(const uint4*)(Xb + (size_t)grow * K + kb + q * 8);
            int k0 = q * 8;
            Xs[k0 + 0][r] = bflo(v.x); Xs[k0 + 1][r] = bfhi(v.x);
            Xs[k0 + 2][r] = bflo(v.y); Xs[k0 + 3][r] = bfhi(v.y);
            Xs[k0 + 4][r] = bflo(v.z); Xs[k0 + 5][r] = bfhi(v.z);
            Xs[k0 + 6][r] = bflo(v.w); Xs[k0 + 7][r] = bfhi(v.w);
        }
#pragma unroll
        for (int it = 0; it < 2; ++it) {
            int idx = t + 256 * it;           // 0..511 float4s
            ((float4*)Ws)[idx] = ((const float4*)(W + (size_t)kb * 64))[idx];
        }
        __syncthreads();
#pragma unroll
        for (int k = 0; k < BK; ++k) {
            float4 xa = *(const float4*)&Xs[k][tm * 8];
            float4 xb = *(const float4*)&Xs[k][tm * 8 + 4];
            float4 w = *(const float4*)&Ws[k][tn * 4];
            float xs[8] = {xa.x, xa.y, xa.z, xa.w, xb.x, xb.y, xb.z, xb.w};
#pragma unroll
            for (int i = 0; i < 8; ++i) {
                acc[i][0] = fmaf(xs[i], w.x, acc[i][0]);
                acc[i][1] = fmaf(xs[i], w.y, acc[i][1]);
                acc[i][2] = fmaf(xs[i], w.z, acc[i][2]);
                acc[i][3] = fmaf(xs[i], w.w, acc[i][3]);
            }
        }
        __syncthreads();
    }
#pragma unroll
    for (int i = 0; i < 8; ++i) {
        int grow = bm + tm * 8 + i;
        if (grow < N) {
            float s = dinv[grow];
            ushort4 v;
            v.x = f2bf(acc[i][0] * s);
            v.y = f2bf(acc[i][1] * s);
            v.z = f2bf(acc[i][2] * s);
            v.w = f2bf(acc[i][3] * s);
            *(ushort4*)(outb + (size_t)grow * 64 + tn * 4) = v;
        }
    }
}

// Gather-aggregate + fused postproc. 8 lanes/node; lane l owns channels
// [8l, 8l+8) as one uint4 (4 packed bf16 pairs). fp32 accumulate.
// acc init = src[node] (self loop). MLP-unrolled x8 (+x4 tail).
// mode 1: relu + bf16 out (dstq). mode 0: fp32 out (dstf).
__global__ __launch_bounds__(256) void k_gather(
    const uint4* __restrict__ srcq, const int* __restrict__ eros,
    const int* __restrict__ start, const int* __restrict__ cntarr,
    const float* __restrict__ dinv, const float* __restrict__ bias,
    float* __restrict__ dstf, uint4* __restrict__ dstq, int N, int mode) {
    int idx = blockIdx.x * 256 + threadIdx.x;
    int node = idx >> 3;
    if (node >= N) return;
    int l = idx & 7;

    uint4 sv = srcq[(size_t)node * 8 + l];  // self loop
    float a0 = bflo(sv.x), a1 = bfhi(sv.x);
    float a2 = bflo(sv.y), a3 = bfhi(sv.y);
    float a4 = bflo(sv.z), a5 = bfhi(sv.z);
    float a6 = bflo(sv.w), a7 = bfhi(sv.w);

    int e = start[node];
    int eend = e + cntarr[node];
    for (; e + 8 <= eend; e += 8) {
        uint4 v[8];
#pragma unroll
        for (int j = 0; j < 8; ++j) {
            int r = eros[e + j];
            v[j] = srcq[(size_t)r * 8 + l];
        }
#pragma unroll
        for (int j = 0; j < 8; ++j) {
            a0 += bflo(v[j].x); a1 += bfhi(v[j].x);
            a2 += bflo(v[j].y); a3 += bfhi(v[j].y);
            a4 += bflo(v[j].z); a5 += bfhi(v[j].z);
            a6 += bflo(v[j].w); a7 += bfhi(v[j].w);
        }
    }
    for (; e + 4 <= eend; e += 4) {
        uint4 v[4];
#pragma unroll
        for (int j = 0; j < 4; ++j) {
            int r = eros[e + j];
            v[j] = srcq[(size_t)r * 8 + l];
        }
#pragma unroll
        for (int j = 0; j < 4; ++j) {
            a0 += bflo(v[j].x); a1 += bfhi(v[j].x);
            a2 += bflo(v[j].y); a3 += bfhi(v[j].y);
            a4 += bflo(v[j].z); a5 += bfhi(v[j].z);
            a6 += bflo(v[j].w); a7 += bfhi(v[j].w);
        }
    }
    for (; e < eend; ++e) {
        int r = eros[e];
        uint4 v = srcq[(size_t)r * 8 + l];
        a0 += bflo(v.x); a1 += bfhi(v.x);
        a2 += bflo(v.y); a3 += bfhi(v.y);
        a4 += bflo(v.z); a5 += bfhi(v.z);
        a6 += bflo(v.w); a7 += bfhi(v.w);
    }
    float sc = dinv[node];
    const float4* bp = (const float4*)bias;
    float4 b0 = bp[l * 2], b1 = bp[l * 2 + 1];
    a0 = a0 * sc + b0.x; a1 = a1 * sc + b0.y;
    a2 = a2 * sc + b0.z; a3 = a3 * sc + b0.w;
    a4 = a4 * sc + b1.x; a5 = a5 * sc + b1.y;
    a6 = a6 * sc + b1.z; a7 = a7 * sc + b1.w;
    if (mode) {  // relu + bf16 pack
        a0 = fmaxf(a0, 0.f); a1 = fmaxf(a1, 0.f);
        a2 = fmaxf(a2, 0.f); a3 = fmaxf(a3, 0.f);
        a4 = fmaxf(a4, 0.f); a5 = fmaxf(a5, 0.f);
        a6 = fmaxf(a6, 0.f); a7 = fmaxf(a7, 0.f);
        uint4 o;
        o.x = (unsigned)f2bf(a0) | ((unsigned)f2bf(a1) << 16);
        o.y = (unsigned)f2bf(a2) | ((unsigned)f2bf(a3) << 16);
        o.z = (unsigned)f2bf(a4) | ((unsigned)f2bf(a5) << 16);
        o.w = (unsigned)f2bf(a6) | ((unsigned)f2bf(a7) << 16);
        dstq[(size_t)node * 8 + l] = o;
    } else {
        float4 o0 = make_float4(a0, a1, a2, a3);
        float4 o1 = make_float4(a4, a5, a6, a7);
        float4* d = (float4*)(dstf + (size_t)node * 64 + l * 8);
        d[0] = o0;
        d[1] = o1;
    }
}

extern "C" void kernel_launch(void* const* d_in, const int* in_sizes, int n_in,
                              void* d_out, int out_size, void* d_ws, size_t ws_size,
                              hipStream_t stream) {
    const float* x = (const float*)d_in[0];
    const int* ei = (const int*)d_in[1];  // int32 per harness contract, [2, E]
    const float* W1 = (const float*)d_in[2];
    const float* b1 = (const float*)d_in[3];
    const float* W2 = (const float*)d_in[4];
    const float* b2 = (const float*)d_in[5];

    int N = in_sizes[0] / 128;  // 100000
    int E = in_sizes[1] / 2;    // 1600000
    const int* row = ei;
    const int* col = ei + E;
    int nb = (N + (1 << BKT_SH) - 1) >> BKT_SH;  // 782 buckets

    char* ws = (char*)d_ws;
    int* cursor = (int*)ws;                          // nb ints @ 0
    int* start = (int*)(ws + (1 << 16));             // N ints @ 64 KB
    int* cntarr = (int*)(ws + (1 << 19));            // N ints @ 512 KB
    float* dinv = (float*)(ws + 960 * 1024);         // N floats @ 960 KB
    unsigned* bentries = (unsigned*)(ws + (2 << 20));    // nb*CAP u32 @ 2 MB (12.8 MB)
    unsigned short* Ab = (unsigned short*)(ws + (15 << 20));  // N*64 bf16 @ 15 MB (12.8 MB)
    unsigned short* Hb = (unsigned short*)d_out;     // bf16 h2 scratch in d_out
    float* OUTF = (float*)d_out;                     // final fp32 output

    int gemmblk = (N + BM - 1) / BM;       // 782
    int binblk = (E + CHUNK - 1) / CHUNK;  // 261
    int gblk = (N * 8 + 255) / 256;        // 3125

    // --- CSR build (padded buckets; once, shared by both layers) ---
    k_zero_i<<<(nb + 255) / 256, 256, 0, stream>>>(cursor, nb);
    k_bin<<<binblk, 256, 0, stream>>>(row, col, cursor, bentries, E);
    k_bucket_sort<<<nb, 256, 0, stream>>>(bentries, cursor, start, cntarr, dinv, N);

    // Layer 1: Ab = bf16((X@W1)*dinv); Hb = bf16(relu(gather(Ab)*dinv + b1))
    k_gemm_f32in<<<gemmblk, 256, 0, stream>>>(x, W1, dinv, Ab, N, 128);
    k_gather<<<gblk, 256, 0, stream>>>((const uint4*)Ab, (const int*)bentries,
                                       start, cntarr, dinv, b1,
                                       nullptr, (uint4*)Hb, N, 1);

    // Layer 2: Ab = bf16((Hb@W2)*dinv); d_out = gather(Ab)*dinv + b2 (fp32)
    k_gemm_bf16in<<<gemmblk, 256, 0, stream>>>(Hb, W2, dinv, Ab, N, 64);
    k_gather<<<gblk, 256, 0, stream>>>((const uint4*)Ab, (const int*)bentries,
                                       start, cntarr, dinv, b2,
                                       OUTF, nullptr, N, 0);
}